// Round 6
// baseline (563.866 us; speedup 1.0000x reference)
//
#include <hip/hip_runtime.h>
#include <hip/hip_bf16.h>

// ---------------------------------------------------------------------------
// Transformer block: pre-LN -> QKV GEMM -> masked softmax attention -> MLP ->
// residual -> post-LN -> masked mean pool.
// bs=512, NE=128, F=512, heads=8, d=64. GEMMs in bf16 MFMA 16x16x32.
// Split path (ws >= 258MB): ln -> qkv_gemm -> attn_fused (1 block/batch,
//   8-head loop, double-buffered K/V, in-register softmax+P-transpose) ->
//   mlp_gemm -> pool.
// Fallback path (small ws): round-1 fused kernels (known-passing).
// ---------------------------------------------------------------------------

typedef __bf16 bf16;
typedef __bf16 bf16x8 __attribute__((ext_vector_type(8)));
typedef __bf16 bf16x4 __attribute__((ext_vector_type(4)));
typedef float f32x4 __attribute__((ext_vector_type(4)));
typedef unsigned u32x4 __attribute__((ext_vector_type(4)));

__device__ __forceinline__ f32x4 mfma16(bf16x8 a, bf16x8 b, f32x4 c) {
    return __builtin_amdgcn_mfma_f32_16x16x32_bf16(a, b, c, 0, 0, 0);
}

// async global->LDS copy, 16B per lane. LDS dest = wave-uniform base + lane*16.
typedef const unsigned int __attribute__((address_space(1)))* gptr_t;
typedef unsigned int __attribute__((address_space(3)))* lptr_t;
__device__ __forceinline__ void gld16(const void* g, void* l) {
    __builtin_amdgcn_global_load_lds((gptr_t)g, (lptr_t)l, 16, 0, 0);
}

__device__ __forceinline__ unsigned pack2(float lo, float hi) {
    unsigned short a = __builtin_bit_cast(unsigned short, (bf16)lo);
    unsigned short b = __builtin_bit_cast(unsigned short, (bf16)hi);
    return (unsigned)a | ((unsigned)b << 16);
}

#define SWZ(byteoff, row) ((byteoff) ^ (((row) & 7) << 4))

// ===========================================================================
// SPLIT PATH
// ===========================================================================

// K0s: weight prep.
// Wqkv_s: tiled [tn(12)][kc(8)][nc(128)][kw(64)], N order: Q(h*64+d) | K | V.
// Wmlp_t: tiled [tn(4)][kc(8)][nc(128)][kw(64)] (same scheme, N=512).
// bQKV: [1536] reordered biases.
__global__ __launch_bounds__(256) void prep_split_kernel(
    const float* __restrict__ Wqk, const float* __restrict__ bqk,
    const float* __restrict__ Wv, const float* __restrict__ bv,
    const float* __restrict__ Wmlp,
    bf16* __restrict__ Wqkv_s, bf16* __restrict__ Wmlp_t, float* __restrict__ bQKV)
{
    int t = blockIdx.x * 256 + threadIdx.x;
    if (t < 524288) {                       // Wqk part, coalesced read
        int k = t >> 10, c = t & 1023;
        int h = c >> 7, w7 = c & 127, d = w7 >> 1, isK = w7 & 1;
        int n = isK * 512 + h * 64 + d;
        int tn = n >> 7, nc = n & 127, kc = k >> 6, kw = k & 63;
        Wqkv_s[((size_t)(tn * 8 + kc) * 128 + nc) * 64 + kw] = (bf16)Wqk[t];
    } else if (t < 786432) {                // Wv part
        int u = t - 524288;
        int k = u >> 9, c = u & 511;
        int n = 1024 + c;
        int tn = n >> 7, nc = n & 127, kc = k >> 6, kw = k & 63;
        Wqkv_s[((size_t)(tn * 8 + kc) * 128 + nc) * 64 + kw] = (bf16)Wv[u];
    } else if (t < 1048576) {               // Wmlp, tiled like Wqkv
        int u = t - 786432;
        int k = u >> 9, c = u & 511;
        int tn = c >> 7, nc = c & 127, kc = k >> 6, kw = k & 63;
        Wmlp_t[((size_t)(tn * 8 + kc) * 128 + nc) * 64 + kw] = (bf16)Wmlp[u];
    } else if (t < 1050112) {               // biases
        int j = t - 1048576;
        int region = j >> 9, w9 = j & 511, h = w9 >> 6, d = w9 & 63;
        float v;
        if (region == 0)      v = bqk[h * 128 + d * 2];
        else if (region == 1) v = bqk[h * 128 + d * 2 + 1];
        else                  v = bv[h * 64 + d];
        bQKV[j] = v;
    }
}

// K1: pre-LN + cast to bf16. One wave per row of 512. (shared by both paths)
__global__ __launch_bounds__(256) void ln_kernel(
    const float* __restrict__ x, const float* __restrict__ g,
    const float* __restrict__ b, bf16* __restrict__ inp)
{
    int row = blockIdx.x * 4 + (threadIdx.x >> 6);
    int lane = threadIdx.x & 63;
    int k0 = lane * 8;
    const float* xr = x + (size_t)row * 512 + k0;
    f32x4 a0 = *(const f32x4*)xr;
    f32x4 a1 = *(const f32x4*)(xr + 4);
    float s = 0.f, ss = 0.f;
#pragma unroll
    for (int i = 0; i < 4; i++) {
        s += a0[i] + a1[i];
        ss += a0[i] * a0[i] + a1[i] * a1[i];
    }
#pragma unroll
    for (int m = 1; m < 64; m <<= 1) {
        s  += __shfl_xor(s, m, 64);
        ss += __shfl_xor(ss, m, 64);
    }
    float mu = s * (1.f / 512.f);
    float rstd = rsqrtf(ss * (1.f / 512.f) - mu * mu + 1e-3f);
    f32x4 g0 = *(const f32x4*)(g + k0);
    f32x4 g1 = *(const f32x4*)(g + k0 + 4);
    f32x4 b0 = *(const f32x4*)(b + k0);
    f32x4 b1 = *(const f32x4*)(b + k0 + 4);
    bf16x8 ov;
#pragma unroll
    for (int i = 0; i < 4; i++) {
        ov[i]     = (bf16)((a0[i] - mu) * rstd * g0[i] + b0[i]);
        ov[i + 4] = (bf16)((a1[i] - mu) * rstd * g1[i] + b1[i]);
    }
    *(bf16x8*)(inp + (size_t)row * 512 + k0) = ov;
}

// K2s: QKV GEMM. M=65536, N=1536, K=512. 128x128 tile, 4 waves (2x2),
// BK=64, single-buffered LDS, global_load_lds staging, XOR-swizzled LDS
// (linear dest + inverse-swizzled source + matching read XOR).
__global__ __launch_bounds__(256) void qkv_gemm_kernel(
    const bf16* __restrict__ inp, const bf16* __restrict__ Wqkv_s,
    const float* __restrict__ bQKV,
    bf16* __restrict__ q, bf16* __restrict__ kbuf, bf16* __restrict__ vt)
{
    __shared__ __align__(16) bf16 As[128 * 64];
    __shared__ __align__(16) bf16 Bs[128 * 64];
    const int bid = blockIdx.x;
    const int idx = (bid & 7) * 768 + (bid >> 3);   // XCD swizzle (6144 % 8 == 0)
    const int tm = idx / 12, tn = idx % 12;
    const int tid = threadIdx.x;
    const int w = tid >> 6, l = tid & 63;
    const int wr = w >> 1, wc = w & 1;
    const int l15 = l & 15, l4 = l >> 4;

    const f32x4 fz = {0.f, 0.f, 0.f, 0.f};
    f32x4 acc[4][4];
#pragma unroll
    for (int m = 0; m < 4; m++)
#pragma unroll
        for (int n = 0; n < 4; n++) acc[m][n] = fz;

    const int arow = l >> 3;                         // 0..7 (== LDS row & 7)
    const int axc = ((l & 7) ^ arow) * 8;            // inverse-swizzled col
    const bf16* Abase = inp + (size_t)(tm * 128) * 512;
    const int rsw = (l15 & 7) << 4;                  // read-side XOR (bytes)

    for (int kc = 0; kc < 8; kc++) {
#pragma unroll
        for (int i = 0; i < 4; i++) {
            int rg = (i * 4 + w) * 8;
            gld16(Abase + (size_t)(rg + arow) * 512 + kc * 64 + axc,
                  As + (i * 4 + w) * 512);
        }
        const bf16* Bbase = Wqkv_s + (size_t)(tn * 8 + kc) * 8192;
#pragma unroll
        for (int i = 0; i < 4; i++) {
            gld16(Bbase + (size_t)((i * 4 + w) * 8 + arow) * 64 + axc,
                  Bs + (i * 4 + w) * 512);
        }
        __syncthreads();
#pragma unroll
        for (int kk = 0; kk < 2; kk++) {
            const int kb = (kk * 64 + l4 * 16) ^ rsw;  // swizzled byte offset
            bf16x8 af[4], bfr[4];
#pragma unroll
            for (int m = 0; m < 4; m++)
                af[m] = *(const bf16x8*)((const char*)As + (wr * 64 + m * 16 + l15) * 128 + kb);
#pragma unroll
            for (int n = 0; n < 4; n++)
                bfr[n] = *(const bf16x8*)((const char*)Bs + (wc * 64 + n * 16 + l15) * 128 + kb);
#pragma unroll
            for (int m = 0; m < 4; m++)
#pragma unroll
                for (int n = 0; n < 4; n++)
                    acc[m][n] = mfma16(af[m], bfr[n], acc[m][n]);
        }
        __syncthreads();
    }

    const int colBase = tn * 128 + wc * 64;
    const int mrowBase = tm * 128 + wr * 64;
#pragma unroll
    for (int n = 0; n < 4; n++) {
        int col = colBase + n * 16 + l15;
        float bias = bQKV[col];
        int within = col & 511, hh = within >> 6, dd = within & 63;
#pragma unroll
        for (int m = 0; m < 4; m++) {
            int mr0 = mrowBase + m * 16 + l4 * 4;
            int bb = mr0 >> 7, e0 = mr0 & 127;
            size_t base = (size_t)(bb * 8 + hh) * 8192;
            if (tn < 4) {
#pragma unroll
                for (int r = 0; r < 4; r++)
                    q[base + (size_t)(e0 + r) * 64 + dd] = (bf16)(acc[m][n][r] + bias);
            } else if (tn < 8) {
#pragma unroll
                for (int r = 0; r < 4; r++) {
                    int e = e0 + r;
                    kbuf[base + (size_t)e * 64 + (dd ^ ((e & 7) << 3))] = (bf16)(acc[m][n][r] + bias);
                }
            } else {
                bf16x4 pk;
#pragma unroll
                for (int r = 0; r < 4; r++) pk[r] = (bf16)(acc[m][n][r] + bias);
                *(bf16x4*)(vt + base + (size_t)dd * 128 + (e0 ^ ((dd & 7) << 3))) = pk;
            }
        }
    }
}

// K3s: fused attention, one block per batch, loop over 8 heads with
// double-buffered K/V LDS staging (stage h+1 while computing h; single
// barrier per head). Swapped QK^T (mfma(K,Q)) puts a full P-row slice in
// each lane -> softmax reduce = 2 shuffles; P converted to PV A-fragments
// in-register (pack2 + 32 shfl), no P LDS buffer.
__global__ __launch_bounds__(512) void attn_fused_kernel(
    const bf16* __restrict__ q, const bf16* __restrict__ kbuf,
    const bf16* __restrict__ vt, const float* __restrict__ mask,
    bf16* __restrict__ att)
{
    __shared__ __align__(16) char Ks[2][128 * 128];   // [buf][krow][64d] swizzled
    __shared__ __align__(16) char VTs[2][64 * 256];   // [buf][d][128e] swizzled
    __shared__ float mrow[128];

    const int b = blockIdx.x;
    const size_t bh0 = (size_t)b * 8;
    const int tid = threadIdx.x;
    const int w = tid >> 6, l = tid & 63;
    const int l15 = l & 15, l4 = l >> 4, R0 = w * 16;

    if (tid < 128) mrow[tid] = mask[b * 128 + tid];

    // stage head 0 into buffer 0
    {
        const bf16* kb = kbuf + bh0 * 8192;
        const bf16* vb = vt + bh0 * 8192;
#pragma unroll
        for (int i = 0; i < 2; i++) {
            gld16(kb + ((i * 8 + w) * 64 + l) * 8, (bf16*)Ks[0] + (i * 8 + w) * 512);
            gld16(vb + ((i * 8 + w) * 64 + l) * 8, (bf16*)VTs[0] + (i * 8 + w) * 512);
        }
    }
    // prefetch Q for head 0
    const bf16* qp0 = q + bh0 * 8192 + (size_t)(R0 + l15) * 64 + l4 * 8;
    bf16x8 afn0 = *(const bf16x8*)(qp0);
    bf16x8 afn1 = *(const bf16x8*)(qp0 + 32);
    __syncthreads();

    const f32x4 fz = {0.f, 0.f, 0.f, 0.f};
    for (int h = 0; h < 8; h++) {
        const int cur = h & 1;
        bf16x8 af0 = afn0, af1 = afn1;
        // issue next head's K/V staging + Q prefetch (hidden under compute)
        if (h < 7) {
            const bf16* kb = kbuf + (bh0 + h + 1) * 8192;
            const bf16* vb = vt + (bh0 + h + 1) * 8192;
#pragma unroll
            for (int i = 0; i < 2; i++) {
                gld16(kb + ((i * 8 + w) * 64 + l) * 8, (bf16*)Ks[cur ^ 1] + (i * 8 + w) * 512);
                gld16(vb + ((i * 8 + w) * 64 + l) * 8, (bf16*)VTs[cur ^ 1] + (i * 8 + w) * 512);
            }
            const bf16* qp = q + (bh0 + h + 1) * 8192 + (size_t)(R0 + l15) * 64 + l4 * 8;
            afn0 = *(const bf16x8*)(qp);
            afn1 = *(const bf16x8*)(qp + 32);
        }

        // ---- swapped QK^T: accL[nt][r] = S[q=R0+l15][k=nt*16+l4*4+r]
        f32x4 accL[8];
#pragma unroll
        for (int n = 0; n < 8; n++) accL[n] = fz;
#pragma unroll
        for (int ks = 0; ks < 2; ks++) {
            bf16x8 bq = ks ? af1 : af0;
            const int k2 = ks * 64 + l4 * 16;
#pragma unroll
            for (int nt = 0; nt < 8; nt++) {
                const int krow = nt * 16 + l15;
                bf16x8 kf = *(const bf16x8*)(Ks[cur] + krow * 128 + (k2 ^ ((krow & 7) << 4)));
                accL[nt] = mfma16(kf, bq, accL[nt]);
            }
        }

        // ---- masked softmax along k (lane-local 32 vals + xor16/32 reduce)
        float mx = -1e30f;
#pragma unroll
        for (int nt = 0; nt < 8; nt++)
#pragma unroll
            for (int r = 0; r < 4; r++) {
                float mk = mrow[nt * 16 + l4 * 4 + r];
                float v = accL[nt][r] * 0.125f - (1.0f - mk) * 1e10f;
                accL[nt][r] = v;
                mx = fmaxf(mx, v);
            }
        mx = fmaxf(mx, __shfl_xor(mx, 16, 64));
        mx = fmaxf(mx, __shfl_xor(mx, 32, 64));
        float sum = 0.f;
#pragma unroll
        for (int nt = 0; nt < 8; nt++)
#pragma unroll
            for (int r = 0; r < 4; r++) {
                float mk = mrow[nt * 16 + l4 * 4 + r];
                float e = __expf(accL[nt][r] - mx) * mk;
                accL[nt][r] = e;
                sum += e;
            }
        sum += __shfl_xor(sum, 16, 64);
        sum += __shfl_xor(sum, 32, 64);
        const float inv = 1.0f / (sum + 1e-10f);

        // ---- pack P row slice to bf16 pairs: pk[nt][qq] = (P[r=2qq], P[r=2qq+1])
        unsigned pk[8][2];
#pragma unroll
        for (int nt = 0; nt < 8; nt++)
#pragma unroll
            for (int qq = 0; qq < 2; qq++)
                pk[nt][qq] = pack2(accL[nt][2 * qq] * inv, accL[nt][2 * qq + 1] * inv);

        // ---- PV: in-register P transpose -> A-fragments, B from VTs LDS
        f32x4 accO[4];
#pragma unroll
        for (int n = 0; n < 4; n++) accO[n] = fz;
        const int glo = l15 + ((l4 & 1) << 5);   // src lane base: l15 + 16*2*(l4&1)
#pragma unroll
        for (int ks = 0; ks < 4; ks++) {
            u32x4 pa4;
#pragma unroll
            for (int p = 0; p < 4; p++) {
                int srcl = glo + ((p >> 1) << 4);
                unsigned va = (unsigned)__shfl((int)pk[2 * ks][p & 1], srcl, 64);
                unsigned vb = (unsigned)__shfl((int)pk[2 * ks + 1][p & 1], srcl, 64);
                pa4[p] = (l4 & 2) ? vb : va;
            }
            bf16x8 pa = __builtin_bit_cast(bf16x8, pa4);
            const int e2 = ks * 64 + l4 * 16;
#pragma unroll
            for (int nt = 0; nt < 4; nt++) {
                const int d = nt * 16 + l15;
                bf16x8 vf = *(const bf16x8*)(VTs[cur] + d * 256 + (e2 ^ ((d & 7) << 4)));
                accO[nt] = mfma16(pa, vf, accO[nt]);
            }
        }

        // ---- store this head's output
        bf16* outp = att + (size_t)(b * 128) * 512 + h * 64;
#pragma unroll
        for (int nt = 0; nt < 4; nt++) {
            const int d = nt * 16 + l15;
#pragma unroll
            for (int r = 0; r < 4; r++) {
                const int e = R0 + l4 * 4 + r;
                outp[(size_t)e * 512 + d] = (bf16)accO[nt][r];
            }
        }
        __syncthreads();   // drains stage loads; next head reads cur^1
    }
}

// K4s: MLP GEMM. M=65536, N=512, K=512. Same structure as qkv_gemm.
// Writes y = att@Wmlp + bmlp as f32 (residual + LN + pool happen in K5s).
__global__ __launch_bounds__(256) void mlp_gemm_kernel(
    const bf16* __restrict__ att, const bf16* __restrict__ Wmlp_t,
    const float* __restrict__ bmlp, float* __restrict__ y)
{
    __shared__ __align__(16) bf16 As[128 * 64];
    __shared__ __align__(16) bf16 Bs[128 * 64];
    const int bid = blockIdx.x;
    const int idx = (bid & 7) * 256 + (bid >> 3);   // XCD swizzle (2048 % 8 == 0)
    const int tm = idx >> 2, tn = idx & 3;
    const int tid = threadIdx.x;
    const int w = tid >> 6, l = tid & 63;
    const int wr = w >> 1, wc = w & 1;
    const int l15 = l & 15, l4 = l >> 4;

    const f32x4 fz = {0.f, 0.f, 0.f, 0.f};
    f32x4 acc[4][4];
#pragma unroll
    for (int m = 0; m < 4; m++)
#pragma unroll
        for (int n = 0; n < 4; n++) acc[m][n] = fz;

    const int arow = l >> 3;
    const int axc = ((l & 7) ^ arow) * 8;
    const bf16* Abase = att + (size_t)(tm * 128) * 512;
    const int rsw = (l15 & 7) << 4;

    for (int kc = 0; kc < 8; kc++) {
#pragma unroll
        for (int i = 0; i < 4; i++) {
            int rg = (i * 4 + w) * 8;
            gld16(Abase + (size_t)(rg + arow) * 512 + kc * 64 + axc,
                  As + (i * 4 + w) * 512);
        }
        const bf16* Bbase = Wmlp_t + (size_t)(tn * 8 + kc) * 8192;
#pragma unroll
        for (int i = 0; i < 4; i++) {
            gld16(Bbase + (size_t)((i * 4 + w) * 8 + arow) * 64 + axc,
                  Bs + (i * 4 + w) * 512);
        }
        __syncthreads();
#pragma unroll
        for (int kk = 0; kk < 2; kk++) {
            const int kb = (kk * 64 + l4 * 16) ^ rsw;
            bf16x8 af[4], bfr[4];
#pragma unroll
            for (int m = 0; m < 4; m++)
                af[m] = *(const bf16x8*)((const char*)As + (wr * 64 + m * 16 + l15) * 128 + kb);
#pragma unroll
            for (int n = 0; n < 4; n++)
                bfr[n] = *(const bf16x8*)((const char*)Bs + (wc * 64 + n * 16 + l15) * 128 + kb);
#pragma unroll
            for (int m = 0; m < 4; m++)
#pragma unroll
                for (int n = 0; n < 4; n++)
                    acc[m][n] = mfma16(af[m], bfr[n], acc[m][n]);
        }
        __syncthreads();
    }

    const int colBase = tn * 128 + wc * 64;
    const int mrowBase = tm * 128 + wr * 64;
#pragma unroll
    for (int n = 0; n < 4; n++) {
        int col = colBase + n * 16 + l15;
        float bias = bmlp[col];
#pragma unroll
        for (int m = 0; m < 4; m++) {
            int row0 = mrowBase + m * 16 + l4 * 4;
#pragma unroll
            for (int r = 0; r < 4; r++)
                y[(size_t)(row0 + r) * 512 + col] = acc[m][n][r] + bias;
        }
    }
}

// K5s: per-batch residual + post-LN + masked mean pool (memory-bound).
__global__ __launch_bounds__(512) void pool_kernel(
    const float* __restrict__ y, const float* __restrict__ x,
    const float* __restrict__ mask, const float* __restrict__ gpost,
    const float* __restrict__ bpost, float* __restrict__ out)
{
    __shared__ float partial[8][512];
    __shared__ float mrow[128];
    __shared__ float msum_s;

    const int b = blockIdx.x;
    const int tid = threadIdx.x;
    const int w = tid >> 6, l = tid & 63;
    const int k0 = l * 8;

    if (tid < 128) mrow[tid] = mask[b * 128 + tid];
    __syncthreads();
    if (w == 0) {
        float v = mrow[l] + mrow[64 + l];
#pragma unroll
        for (int m = 1; m < 64; m <<= 1) v += __shfl_xor(v, m, 64);
        if (l == 0) msum_s = v;
    }

    f32x4 g0 = *(const f32x4*)(gpost + k0);
    f32x4 g1 = *(const f32x4*)(gpost + k0 + 4);
    f32x4 b0 = *(const f32x4*)(bpost + k0);
    f32x4 b1 = *(const f32x4*)(bpost + k0 + 4);

    f32x4 a0 = {0.f, 0.f, 0.f, 0.f}, a1 = {0.f, 0.f, 0.f, 0.f};
    for (int i = 0; i < 16; i++) {
        int row = w * 16 + i;
        const float* yr = y + ((size_t)(b * 128 + row)) * 512 + k0;
        const float* xr = x + ((size_t)(b * 128 + row)) * 512 + k0;
        f32x4 v0 = *(const f32x4*)yr + *(const f32x4*)xr;
        f32x4 v1 = *(const f32x4*)(yr + 4) + *(const f32x4*)(xr + 4);
        float s = 0.f, ss = 0.f;
#pragma unroll
        for (int j = 0; j < 4; j++) {
            s += v0[j] + v1[j];
            ss += v0[j] * v0[j] + v1[j] * v1[j];
        }
#pragma unroll
        for (int m = 1; m < 64; m <<= 1) {
            s  += __shfl_xor(s, m, 64);
            ss += __shfl_xor(ss, m, 64);
        }
        float mu = s * (1.f / 512.f);
        float rstd = rsqrtf(ss * (1.f / 512.f) - mu * mu + 1e-3f);
        float mr = mrow[row];
#pragma unroll
        for (int j = 0; j < 4; j++) {
            a0[j] += ((v0[j] - mu) * rstd * g0[j] + b0[j]) * mr;
            a1[j] += ((v1[j] - mu) * rstd * g1[j] + b1[j]) * mr;
        }
    }
#pragma unroll
    for (int j = 0; j < 4; j++) {
        partial[w][k0 + j]     = a0[j];
        partial[w][k0 + 4 + j] = a1[j];
    }
    __syncthreads();
    float t = 0.f;
#pragma unroll
    for (int ww = 0; ww < 8; ww++) t += partial[ww][tid];
    out[(size_t)b * 512 + tid] = t / (msum_s + 1e-5f);
}

// ===========================================================================
// FALLBACK PATH — round-1 kernels, verbatim (known-passing).
// ===========================================================================
__global__ __launch_bounds__(256) void prep_kernel(
    const float* __restrict__ Wqk, const float* __restrict__ bqk,
    const float* __restrict__ Wv, const float* __restrict__ bv,
    const float* __restrict__ Wmlp,
    bf16* __restrict__ Wqkv_t, bf16* __restrict__ Wmlp_t, float* __restrict__ bQKV)
{
    int t = blockIdx.x * 256 + threadIdx.x;
    const int NQKV = 8 * 192 * 512;
    if (t < NQKV) {
        int h = t / (192 * 512);
        int rem = t - h * (192 * 512);
        int n = rem >> 9;
        int k = rem & 511;
        float v;
        if (n < 64)       v = Wqk[k * 1024 + h * 128 + n * 2];
        else if (n < 128) v = Wqk[k * 1024 + h * 128 + (n - 64) * 2 + 1];
        else              v = Wv[k * 512 + h * 64 + (n - 128)];
        Wqkv_t[t] = (bf16)v;
    } else {
        int u = t - NQKV;
        if (u < 512 * 512) {
            int col = u >> 9, k = u & 511;
            Wmlp_t[u] = (bf16)Wmlp[k * 512 + col];
        } else {
            int j = u - 512 * 512;
            if (j < 1536) {
                int h = j / 192, n = j - h * 192;
                float v;
                if (n < 64)       v = bqk[h * 128 + n * 2];
                else if (n < 128) v = bqk[h * 128 + (n - 64) * 2 + 1];
                else              v = bv[h * 64 + (n - 128)];
                bQKV[j] = v;
            }
        }
    }
}

__global__ __launch_bounds__(512) void attn_kernel(
    const bf16* __restrict__ inp, const float* __restrict__ mask,
    const bf16* __restrict__ Wqkv_t, const float* __restrict__ bQKV,
    bf16* __restrict__ att)
{
    __shared__ __align__(16) char Qs[128 * 128];
    __shared__ __align__(16) char Ks[128 * 128];
    __shared__ __align__(16) char VTs[64 * 256];
    __shared__ __align__(16) char Ps[128 * 256];
    __shared__ float mrow[128];

    const int bid = blockIdx.x;
    const int b = bid & 511;
    const int h = bid >> 9;
    const int tid = threadIdx.x;
    const int w = tid >> 6, l = tid & 63;
    const int l15 = l & 15, l4 = l >> 4;
    const int R0 = w * 16;

    if (tid < 128) mrow[tid] = mask[b * 128 + tid];

    const bf16* A  = inp + (size_t)(b * 128) * 512;
    const bf16* Wh = Wqkv_t + (size_t)h * 192 * 512;
    const f32x4 fz = {0.f, 0.f, 0.f, 0.f};

    f32x4 acc[12];
#pragma unroll
    for (int n = 0; n < 12; n++) acc[n] = fz;
    const bf16* aptr = A + (size_t)(R0 + l15) * 512 + l4 * 8;
#pragma unroll 4
    for (int ks = 0; ks < 16; ks++) {
        bf16x8 af = *(const bf16x8*)(aptr + ks * 32);
#pragma unroll
        for (int n = 0; n < 12; n++) {
            bf16x8 bfr = *(const bf16x8*)(Wh + (size_t)(n * 16 + l15) * 512 + ks * 32 + l4 * 8);
            acc[n] = mfma16(af, bfr, acc[n]);
        }
    }
#pragma unroll
    for (int n = 0; n < 12; n++) {
        int col = n * 16 + l15;
        float bias = bQKV[h * 192 + col];
#pragma unroll
        for (int r = 0; r < 4; r++) {
            int row = R0 + l4 * 4 + r;
            bf16 val = (bf16)(acc[n][r] + bias);
            if (n < 4) {
                *(bf16*)(Qs + row * 128 + SWZ(col * 2, row)) = val;
            } else if (n < 8) {
                *(bf16*)(Ks + row * 128 + SWZ((col - 64) * 2, row)) = val;
            } else {
                int d = col - 128;
                *(bf16*)(VTs + d * 256 + SWZ(row * 2, d)) = val;
            }
        }
    }
    __syncthreads();

    f32x4 accL[8];
#pragma unroll
    for (int n = 0; n < 8; n++) accL[n] = fz;
#pragma unroll
    for (int ks = 0; ks < 2; ks++) {
        int k = ks * 32 + l4 * 8;
        int qrow = R0 + l15;
        bf16x8 af = *(const bf16x8*)(Qs + qrow * 128 + SWZ(k * 2, qrow));
#pragma unroll
        for (int nt = 0; nt < 8; nt++) {
            int krow = nt * 16 + l15;
            bf16x8 bfr = *(const bf16x8*)(Ks + krow * 128 + SWZ(k * 2, krow));
            accL[nt] = mfma16(af, bfr, accL[nt]);
        }
    }
    float pv[32];
#pragma unroll
    for (int r = 0; r < 4; r++) {
        float mx = -1e30f;
#pragma unroll
        for (int nt = 0; nt < 8; nt++) {
            int colk = nt * 16 + l15;
            float v = accL[nt][r] * 0.125f - (1.0f - mrow[colk]) * 1e10f;
            pv[nt * 4 + r] = v;
            mx = fmaxf(mx, v);
        }
#pragma unroll
        for (int m = 1; m < 16; m <<= 1) mx = fmaxf(mx, __shfl_xor(mx, m, 64));
        float sum = 0.f;
#pragma unroll
        for (int nt = 0; nt < 8; nt++) {
            int colk = nt * 16 + l15;
            float e = __expf(pv[nt * 4 + r] - mx) * mrow[colk];
            pv[nt * 4 + r] = e;
            sum += e;
        }
#pragma unroll
        for (int m = 1; m < 16; m <<= 1) sum += __shfl_xor(sum, m, 64);
        float inv = 1.0f / (sum + 1e-10f);
        int prow = R0 + l4 * 4 + r;
#pragma unroll
        for (int nt = 0; nt < 8; nt++) {
            bf16 pb = (bf16)(pv[nt * 4 + r] * inv);
            *(bf16*)(Ps + prow * 256 + SWZ((nt * 16 + l15) * 2, prow)) = pb;
        }
    }
    __syncthreads();

    f32x4 accO[4];
#pragma unroll
    for (int n = 0; n < 4; n++) accO[n] = fz;
#pragma unroll
    for (int ks = 0; ks < 4; ks++) {
        int k = ks * 32 + l4 * 8;
        int prow = R0 + l15;
        bf16x8 af = *(const bf16x8*)(Ps + prow * 256 + SWZ(k * 2, prow));
#pragma unroll
        for (int nt = 0; nt < 4; nt++) {
            int d = nt * 16 + l15;
            bf16x8 bfr = *(const bf16x8*)(VTs + d * 256 + SWZ(k * 2, d));
            accO[nt] = mfma16(af, bfr, accO[nt]);
        }
    }
    bf16* outp = att + (size_t)(b * 128) * 512 + h * 64;
#pragma unroll
    for (int nt = 0; nt < 4; nt++) {
        int d = nt * 16 + l15;
#pragma unroll
        for (int r = 0; r < 4; r++) {
            int e = R0 + l4 * 4 + r;
            outp[(size_t)e * 512 + d] = (bf16)accO[nt][r];
        }
    }
}

__global__ __launch_bounds__(512) void mlp_kernel(
    const bf16* __restrict__ att, const bf16* __restrict__ Wmlp_t,
    const float* __restrict__ bmlp, const float* __restrict__ x,
    const float* __restrict__ mask, const float* __restrict__ gpost,
    const float* __restrict__ bpost, float* __restrict__ out)
{
    __shared__ float pool[512];
    __shared__ float gb[1024];
    __shared__ float mrow[128];
    __shared__ float msum_s;

    const int b = blockIdx.x;
    const int tid = threadIdx.x;
    const int w = tid >> 6, l = tid & 63;
    const int l15 = l & 15, l4 = l >> 4;
    const int R0 = w * 16;

    pool[tid] = 0.f;
    gb[tid] = gpost[tid];
    gb[512 + tid] = bpost[tid];
    if (tid < 128) mrow[tid] = mask[b * 128 + tid];
    __syncthreads();
    if (w == 0) {
        float v = mrow[l] + mrow[64 + l];
#pragma unroll
        for (int m = 1; m < 64; m <<= 1) v += __shfl_xor(v, m, 64);
        if (l == 0) msum_s = v;
    }

    const f32x4 fz = {0.f, 0.f, 0.f, 0.f};
    f32x4 acc[32];
#pragma unroll
    for (int n = 0; n < 32; n++) acc[n] = fz;
    const bf16* Ab = att + (size_t)(b * 128 + R0 + l15) * 512 + l4 * 8;
#pragma unroll 2
    for (int ks = 0; ks < 16; ks++) {
        bf16x8 af = *(const bf16x8*)(Ab + ks * 32);
#pragma unroll
        for (int nt = 0; nt < 32; nt++) {
            bf16x8 bfr = *(const bf16x8*)(Wmlp_t + (size_t)(nt * 16 + l15) * 512 + ks * 32 + l4 * 8);
            acc[nt] = mfma16(af, bfr, acc[nt]);
        }
    }
#pragma unroll
    for (int nt = 0; nt < 32; nt++) {
        int col = nt * 16 + l15;
        float bb = bmlp[col];
#pragma unroll
        for (int r = 0; r < 4; r++) {
            int row = R0 + l4 * 4 + r;
            acc[nt][r] = acc[nt][r] + bb + x[((size_t)b * 128 + row) * 512 + col];
        }
    }
    float mu[4], rs[4];
#pragma unroll
    for (int r = 0; r < 4; r++) {
        float s = 0.f, ss = 0.f;
#pragma unroll
        for (int nt = 0; nt < 32; nt++) {
            float v = acc[nt][r];
            s += v; ss += v * v;
        }
#pragma unroll
        for (int m = 1; m < 16; m <<= 1) {
            s  += __shfl_xor(s, m, 64);
            ss += __shfl_xor(ss, m, 64);
        }
        float m_ = s * (1.f / 512.f);
        mu[r] = m_;
        rs[r] = rsqrtf(ss * (1.f / 512.f) - m_ * m_ + 1e-3f);
    }
#pragma unroll
    for (int nt = 0; nt < 32; nt++) {
        int col = nt * 16 + l15;
        float g = gb[col], bb = gb[512 + col];
        float s = 0.f;
#pragma unroll
        for (int r = 0; r < 4; r++) {
            int row = R0 + l4 * 4 + r;
            float y = (acc[nt][r] - mu[r]) * rs[r] * g + bb;
            s += y * mrow[row];
        }
        atomicAdd(&pool[col], s);
    }
    __syncthreads();
    out[(size_t)b * 512 + tid] = pool[tid] / (msum_s + 1e-5f);
}

// ---------------------------------------------------------------------------
extern "C" void kernel_launch(void* const* d_in, const int* in_sizes, int n_in,
                              void* d_out, int out_size, void* d_ws, size_t ws_size,
                              hipStream_t stream)
{
    const float* x     = (const float*)d_in[0];
    const float* mask  = (const float*)d_in[1];
    const float* Wqk   = (const float*)d_in[2];
    const float* bqk   = (const float*)d_in[3];
    const float* Wv    = (const float*)d_in[4];
    const float* bv    = (const float*)d_in[5];
    const float* Wmlp  = (const float*)d_in[6];
    const float* bmlp  = (const float*)d_in[7];
    const float* gpre  = (const float*)d_in[8];
    const float* bpre  = (const float*)d_in[9];
    const float* gpost = (const float*)d_in[10];
    const float* bpost = (const float*)d_in[11];
    float* out = (float*)d_out;
    char* ws = (char*)d_ws;

    const size_t NEED_SPLIT = 270538752;   // 256MiB buffers + 2MiB weights + 6KiB bias
    if (ws_size >= NEED_SPLIT) {
        bf16*  q      = (bf16*)ws;                               // 64 MiB
        bf16*  kbuf   = (bf16*)(ws + (size_t)67108864);          // 64 MiB
        bf16*  vt     = (bf16*)(ws + (size_t)134217728);         // 64 MiB
        bf16*  inp    = (bf16*)(ws + (size_t)201326592);         // 64 MiB (att aliases)
        bf16*  att    = inp;
        float* y      = (float*)ws;                              // 128 MiB, aliases q/kbuf (dead)
        bf16*  Wqkv_s = (bf16*)(ws + (size_t)268435456);         // 1.5 MiB
        bf16*  Wmlp_t = (bf16*)(ws + (size_t)270008320);         // 0.5 MiB
        float* bQKV   = (float*)(ws + (size_t)270532608);        // 6 KiB

        prep_split_kernel<<<4103, 256, 0, stream>>>(Wqk, bqk, Wv, bv, Wmlp, Wqkv_s, Wmlp_t, bQKV);
        ln_kernel<<<16384, 256, 0, stream>>>(x, gpre, bpre, inp);
        qkv_gemm_kernel<<<6144, 256, 0, stream>>>(inp, Wqkv_s, bQKV, q, kbuf, vt);
        attn_fused_kernel<<<512, 512, 0, stream>>>(q, kbuf, vt, mask, att);
        mlp_gemm_kernel<<<2048, 256, 0, stream>>>(att, Wmlp_t, bmlp, y);
        pool_kernel<<<512, 512, 0, stream>>>(y, x, mask, gpost, bpost, out);
    } else {
        bf16*  inp    = (bf16*)ws;                                   // 64 MiB
        bf16*  att    = (bf16*)(ws + 67108864);                      // 64 MiB
        bf16*  Wqkv_t = (bf16*)(ws + 134217728);                     // 1.5 MiB
        bf16*  Wmlp_t = (bf16*)(ws + 134217728 + 1572864);           // 0.5 MiB
        float* bQKV   = (float*)(ws + 134217728 + 1572864 + 524288); // 6 KiB

        prep_kernel<<<4103, 256, 0, stream>>>(Wqk, bqk, Wv, bv, Wmlp, Wqkv_t, Wmlp_t, bQKV);
        ln_kernel<<<16384, 256, 0, stream>>>(x, gpre, bpre, inp);
        attn_kernel<<<4096, 512, 0, stream>>>(inp, mask, Wqkv_t, bQKV, att);
        mlp_kernel<<<512, 512, 0, stream>>>(att, Wmlp_t, bmlp, x, mask, gpost, bpost, out);
    }
}

// Round 7
// 532.725 us; speedup vs baseline: 1.0585x; 1.0585x over previous
//
#include <hip/hip_runtime.h>
#include <hip/hip_bf16.h>

// ---------------------------------------------------------------------------
// Transformer block: pre-LN -> QKV GEMM -> masked softmax attention -> MLP ->
// residual -> post-LN -> masked mean pool.
// bs=512, NE=128, F=512, heads=8, d=64. GEMMs in bf16 MFMA 16x16x32.
// Split path (ws >= 258MB): ln -> qkv_gemm (2-phase double-buffered LDS) ->
//   attn_fused (1 block/batch, dbuf K/V, in-register softmax) ->
//   mlp_gemm (dbuf, bf16 y) -> pool.
// Fallback path (small ws): round-1 fused kernels (known-passing).
// ---------------------------------------------------------------------------

typedef __bf16 bf16;
typedef __bf16 bf16x8 __attribute__((ext_vector_type(8)));
typedef __bf16 bf16x4 __attribute__((ext_vector_type(4)));
typedef float f32x4 __attribute__((ext_vector_type(4)));
typedef unsigned u32x4 __attribute__((ext_vector_type(4)));

__device__ __forceinline__ f32x4 mfma16(bf16x8 a, bf16x8 b, f32x4 c) {
    return __builtin_amdgcn_mfma_f32_16x16x32_bf16(a, b, c, 0, 0, 0);
}

// async global->LDS copy, 16B per lane. LDS dest = wave-uniform base + lane*16.
typedef const unsigned int __attribute__((address_space(1)))* gptr_t;
typedef unsigned int __attribute__((address_space(3)))* lptr_t;
__device__ __forceinline__ void gld16(const void* g, void* l) {
    __builtin_amdgcn_global_load_lds((gptr_t)g, (lptr_t)l, 16, 0, 0);
}

__device__ __forceinline__ unsigned pack2(float lo, float hi) {
    unsigned short a = __builtin_bit_cast(unsigned short, (bf16)lo);
    unsigned short b = __builtin_bit_cast(unsigned short, (bf16)hi);
    return (unsigned)a | ((unsigned)b << 16);
}

#define SWZ(byteoff, row) ((byteoff) ^ (((row) & 7) << 4))

// ===========================================================================
// SPLIT PATH
// ===========================================================================

// K0s: weight prep, OUTPUT-indexed so global writes are lane-contiguous
// (reads scatter into L2 instead — cheap; old version did 1M scattered
// 2-byte writes).
// Wqkv_s: tiled [tn(12)][kc(8)][nc(128)][kw(64)], N order: Q(h*64+d) | K | V.
// Wmlp_t: tiled [tn(4)][kc(8)][nc(128)][kw(64)] (same scheme, N=512).
// bQKV: [1536] reordered biases.
__global__ __launch_bounds__(256) void prep_split_kernel(
    const float* __restrict__ Wqk, const float* __restrict__ bqk,
    const float* __restrict__ Wv, const float* __restrict__ bv,
    const float* __restrict__ Wmlp,
    bf16* __restrict__ Wqkv_s, bf16* __restrict__ Wmlp_t, float* __restrict__ bQKV)
{
    int t = blockIdx.x * 256 + threadIdx.x;
    if (t < 786432) {                        // Wqkv_s outputs
        int tnkc = t >> 13;                  // (tn*8+kc), 0..95
        int within = t & 8191;
        int nc = within >> 6, kw = within & 63;
        int tn = tnkc >> 3, kc = tnkc & 7;
        int n = tn * 128 + nc, k = kc * 64 + kw;
        float v;
        if (n < 512)       v = Wqk[k * 1024 + (n >> 6) * 128 + (n & 63) * 2];
        else if (n < 1024) { int nn = n - 512;
                             v = Wqk[k * 1024 + (nn >> 6) * 128 + (nn & 63) * 2 + 1]; }
        else               v = Wv[k * 512 + (n - 1024)];
        Wqkv_s[t] = (bf16)v;
    } else if (t < 1048576) {                // Wmlp_t outputs
        int u = t - 786432;
        int tnkc = u >> 13;                  // 0..31
        int within = u & 8191;
        int nc = within >> 6, kw = within & 63;
        int tn = tnkc >> 3, kc = tnkc & 7;
        int n = tn * 128 + nc, k = kc * 64 + kw;
        Wmlp_t[u] = (bf16)Wmlp[k * 512 + n];
    } else if (t < 1050112) {                // biases
        int j = t - 1048576;
        int region = j >> 9, w9 = j & 511, h = w9 >> 6, d = w9 & 63;
        float v;
        if (region == 0)      v = bqk[h * 128 + d * 2];
        else if (region == 1) v = bqk[h * 128 + d * 2 + 1];
        else                  v = bv[h * 64 + d];
        bQKV[j] = v;
    }
}

// K1: pre-LN + cast to bf16. One wave per row of 512. (shared by both paths)
__global__ __launch_bounds__(256) void ln_kernel(
    const float* __restrict__ x, const float* __restrict__ g,
    const float* __restrict__ b, bf16* __restrict__ inp)
{
    int row = blockIdx.x * 4 + (threadIdx.x >> 6);
    int lane = threadIdx.x & 63;
    int k0 = lane * 8;
    const float* xr = x + (size_t)row * 512 + k0;
    f32x4 a0 = *(const f32x4*)xr;
    f32x4 a1 = *(const f32x4*)(xr + 4);
    float s = 0.f, ss = 0.f;
#pragma unroll
    for (int i = 0; i < 4; i++) {
        s += a0[i] + a1[i];
        ss += a0[i] * a0[i] + a1[i] * a1[i];
    }
#pragma unroll
    for (int m = 1; m < 64; m <<= 1) {
        s  += __shfl_xor(s, m, 64);
        ss += __shfl_xor(ss, m, 64);
    }
    float mu = s * (1.f / 512.f);
    float rstd = rsqrtf(ss * (1.f / 512.f) - mu * mu + 1e-3f);
    f32x4 g0 = *(const f32x4*)(g + k0);
    f32x4 g1 = *(const f32x4*)(g + k0 + 4);
    f32x4 b0 = *(const f32x4*)(b + k0);
    f32x4 b1 = *(const f32x4*)(b + k0 + 4);
    bf16x8 ov;
#pragma unroll
    for (int i = 0; i < 4; i++) {
        ov[i]     = (bf16)((a0[i] - mu) * rstd * g0[i] + b0[i]);
        ov[i + 4] = (bf16)((a1[i] - mu) * rstd * g1[i] + b1[i]);
    }
    *(bf16x8*)(inp + (size_t)row * 512 + k0) = ov;
}

// K2s: QKV GEMM. M=65536, N=1536, K=512. 128x128 tile, 4 waves (2x2), BK=64.
// 2-phase double-buffered LDS (T3-minimum): stage kc+1 BEFORE computing kc,
// single barrier per K-step -> stage latency hides under MFMA.
// XOR-swizzled LDS (linear dest + inverse-swizzled source + read XOR).
__global__ __launch_bounds__(256) void qkv_gemm_kernel(
    const bf16* __restrict__ inp, const bf16* __restrict__ Wqkv_s,
    const float* __restrict__ bQKV,
    bf16* __restrict__ q, bf16* __restrict__ kbuf, bf16* __restrict__ vt)
{
    __shared__ __align__(16) bf16 As[2][128 * 64];
    __shared__ __align__(16) bf16 Bs[2][128 * 64];
    const int bid = blockIdx.x;
    const int idx = (bid & 7) * 768 + (bid >> 3);   // XCD swizzle (6144 % 8 == 0)
    const int tm = idx / 12, tn = idx % 12;
    const int tid = threadIdx.x;
    const int w = tid >> 6, l = tid & 63;
    const int wr = w >> 1, wc = w & 1;
    const int l15 = l & 15, l4 = l >> 4;

    const f32x4 fz = {0.f, 0.f, 0.f, 0.f};
    f32x4 acc[4][4];
#pragma unroll
    for (int m = 0; m < 4; m++)
#pragma unroll
        for (int n = 0; n < 4; n++) acc[m][n] = fz;

    const int arow = l >> 3;                         // 0..7 (== LDS row & 7)
    const int axc = ((l & 7) ^ arow) * 8;            // inverse-swizzled col
    const bf16* Abase = inp + (size_t)(tm * 128) * 512;
    const bf16* Bbase0 = Wqkv_s + (size_t)tn * 8 * 8192;
    const int rsw = (l15 & 7) << 4;                  // read-side XOR (bytes)

    // prologue: stage kc=0 into buf 0
#pragma unroll
    for (int i = 0; i < 4; i++) {
        gld16(Abase + (size_t)((i * 4 + w) * 8 + arow) * 512 + axc,
              As[0] + (i * 4 + w) * 512);
        gld16(Bbase0 + (size_t)((i * 4 + w) * 8 + arow) * 64 + axc,
              Bs[0] + (i * 4 + w) * 512);
    }
    __syncthreads();

    for (int kc = 0; kc < 8; kc++) {
        const int cur = kc & 1;
        if (kc < 7) {                                // issue next-tile stage first
#pragma unroll
            for (int i = 0; i < 4; i++) {
                gld16(Abase + (size_t)((i * 4 + w) * 8 + arow) * 512 + (kc + 1) * 64 + axc,
                      As[cur ^ 1] + (i * 4 + w) * 512);
                gld16(Bbase0 + (size_t)(kc + 1) * 8192 + (size_t)((i * 4 + w) * 8 + arow) * 64 + axc,
                      Bs[cur ^ 1] + (i * 4 + w) * 512);
            }
        }
#pragma unroll
        for (int kk = 0; kk < 2; kk++) {
            const int kb = (kk * 64 + l4 * 16) ^ rsw;  // swizzled byte offset
            bf16x8 af[4], bfr[4];
#pragma unroll
            for (int m = 0; m < 4; m++)
                af[m] = *(const bf16x8*)((const char*)As[cur] + (wr * 64 + m * 16 + l15) * 128 + kb);
#pragma unroll
            for (int n = 0; n < 4; n++)
                bfr[n] = *(const bf16x8*)((const char*)Bs[cur] + (wc * 64 + n * 16 + l15) * 128 + kb);
#pragma unroll
            for (int m = 0; m < 4; m++)
#pragma unroll
                for (int n = 0; n < 4; n++)
                    acc[m][n] = mfma16(af[m], bfr[n], acc[m][n]);
        }
        __syncthreads();   // drains this wave's stage loads; swap buffers
    }

    const int colBase = tn * 128 + wc * 64;
    const int mrowBase = tm * 128 + wr * 64;
#pragma unroll
    for (int n = 0; n < 4; n++) {
        int col = colBase + n * 16 + l15;
        float bias = bQKV[col];
        int within = col & 511, hh = within >> 6, dd = within & 63;
#pragma unroll
        for (int m = 0; m < 4; m++) {
            int mr0 = mrowBase + m * 16 + l4 * 4;
            int bb = mr0 >> 7, e0 = mr0 & 127;
            size_t base = (size_t)(bb * 8 + hh) * 8192;
            if (tn < 4) {
#pragma unroll
                for (int r = 0; r < 4; r++)
                    q[base + (size_t)(e0 + r) * 64 + dd] = (bf16)(acc[m][n][r] + bias);
            } else if (tn < 8) {
#pragma unroll
                for (int r = 0; r < 4; r++) {
                    int e = e0 + r;
                    kbuf[base + (size_t)e * 64 + (dd ^ ((e & 7) << 3))] = (bf16)(acc[m][n][r] + bias);
                }
            } else {
                bf16x4 pk;
#pragma unroll
                for (int r = 0; r < 4; r++) pk[r] = (bf16)(acc[m][n][r] + bias);
                *(bf16x4*)(vt + base + (size_t)dd * 128 + (e0 ^ ((dd & 7) << 3))) = pk;
            }
        }
    }
}

// K3s: fused attention, one block per batch, 8-head loop, double-buffered
// K/V staging, swapped QK^T + in-register softmax + in-register P transpose.
__global__ __launch_bounds__(512) void attn_fused_kernel(
    const bf16* __restrict__ q, const bf16* __restrict__ kbuf,
    const bf16* __restrict__ vt, const float* __restrict__ mask,
    bf16* __restrict__ att)
{
    __shared__ __align__(16) char Ks[2][128 * 128];   // [buf][krow][64d] swizzled
    __shared__ __align__(16) char VTs[2][64 * 256];   // [buf][d][128e] swizzled
    __shared__ float mrow[128];

    const int b = blockIdx.x;
    const size_t bh0 = (size_t)b * 8;
    const int tid = threadIdx.x;
    const int w = tid >> 6, l = tid & 63;
    const int l15 = l & 15, l4 = l >> 4, R0 = w * 16;

    if (tid < 128) mrow[tid] = mask[b * 128 + tid];

    {
        const bf16* kb = kbuf + bh0 * 8192;
        const bf16* vb = vt + bh0 * 8192;
#pragma unroll
        for (int i = 0; i < 2; i++) {
            gld16(kb + ((i * 8 + w) * 64 + l) * 8, (bf16*)Ks[0] + (i * 8 + w) * 512);
            gld16(vb + ((i * 8 + w) * 64 + l) * 8, (bf16*)VTs[0] + (i * 8 + w) * 512);
        }
    }
    const bf16* qp0 = q + bh0 * 8192 + (size_t)(R0 + l15) * 64 + l4 * 8;
    bf16x8 afn0 = *(const bf16x8*)(qp0);
    bf16x8 afn1 = *(const bf16x8*)(qp0 + 32);
    __syncthreads();

    const f32x4 fz = {0.f, 0.f, 0.f, 0.f};
    for (int h = 0; h < 8; h++) {
        const int cur = h & 1;
        bf16x8 af0 = afn0, af1 = afn1;
        if (h < 7) {
            const bf16* kb = kbuf + (bh0 + h + 1) * 8192;
            const bf16* vb = vt + (bh0 + h + 1) * 8192;
#pragma unroll
            for (int i = 0; i < 2; i++) {
                gld16(kb + ((i * 8 + w) * 64 + l) * 8, (bf16*)Ks[cur ^ 1] + (i * 8 + w) * 512);
                gld16(vb + ((i * 8 + w) * 64 + l) * 8, (bf16*)VTs[cur ^ 1] + (i * 8 + w) * 512);
            }
            const bf16* qp = q + (bh0 + h + 1) * 8192 + (size_t)(R0 + l15) * 64 + l4 * 8;
            afn0 = *(const bf16x8*)(qp);
            afn1 = *(const bf16x8*)(qp + 32);
        }

        // swapped QK^T: accL[nt][r] = S[q=R0+l15][k=nt*16+l4*4+r]
        f32x4 accL[8];
#pragma unroll
        for (int n = 0; n < 8; n++) accL[n] = fz;
#pragma unroll
        for (int ks = 0; ks < 2; ks++) {
            bf16x8 bq = ks ? af1 : af0;
            const int k2 = ks * 64 + l4 * 16;
#pragma unroll
            for (int nt = 0; nt < 8; nt++) {
                const int krow = nt * 16 + l15;
                bf16x8 kf = *(const bf16x8*)(Ks[cur] + krow * 128 + (k2 ^ ((krow & 7) << 4)));
                accL[nt] = mfma16(kf, bq, accL[nt]);
            }
        }

        // masked softmax along k (lane-local 32 vals + xor16/32 reduce)
        float mx = -1e30f;
#pragma unroll
        for (int nt = 0; nt < 8; nt++)
#pragma unroll
            for (int r = 0; r < 4; r++) {
                float mk = mrow[nt * 16 + l4 * 4 + r];
                float v = accL[nt][r] * 0.125f - (1.0f - mk) * 1e10f;
                accL[nt][r] = v;
                mx = fmaxf(mx, v);
            }
        mx = fmaxf(mx, __shfl_xor(mx, 16, 64));
        mx = fmaxf(mx, __shfl_xor(mx, 32, 64));
        float sum = 0.f;
#pragma unroll
        for (int nt = 0; nt < 8; nt++)
#pragma unroll
            for (int r = 0; r < 4; r++) {
                float mk = mrow[nt * 16 + l4 * 4 + r];
                float e = __expf(accL[nt][r] - mx) * mk;
                accL[nt][r] = e;
                sum += e;
            }
        sum += __shfl_xor(sum, 16, 64);
        sum += __shfl_xor(sum, 32, 64);
        const float inv = 1.0f / (sum + 1e-10f);

        unsigned pk[8][2];
#pragma unroll
        for (int nt = 0; nt < 8; nt++)
#pragma unroll
            for (int qq = 0; qq < 2; qq++)
                pk[nt][qq] = pack2(accL[nt][2 * qq] * inv, accL[nt][2 * qq + 1] * inv);

        // PV: in-register P transpose -> A-fragments, B from VTs LDS
        f32x4 accO[4];
#pragma unroll
        for (int n = 0; n < 4; n++) accO[n] = fz;
        const int glo = l15 + ((l4 & 1) << 5);
#pragma unroll
        for (int ks = 0; ks < 4; ks++) {
            u32x4 pa4;
#pragma unroll
            for (int p = 0; p < 4; p++) {
                int srcl = glo + ((p >> 1) << 4);
                unsigned va = (unsigned)__shfl((int)pk[2 * ks][p & 1], srcl, 64);
                unsigned vb = (unsigned)__shfl((int)pk[2 * ks + 1][p & 1], srcl, 64);
                pa4[p] = (l4 & 2) ? vb : va;
            }
            bf16x8 pa = __builtin_bit_cast(bf16x8, pa4);
            const int e2 = ks * 64 + l4 * 16;
#pragma unroll
            for (int nt = 0; nt < 4; nt++) {
                const int d = nt * 16 + l15;
                bf16x8 vf = *(const bf16x8*)(VTs[cur] + d * 256 + (e2 ^ ((d & 7) << 4)));
                accO[nt] = mfma16(pa, vf, accO[nt]);
            }
        }

        bf16* outp = att + (size_t)(b * 128) * 512 + h * 64;
#pragma unroll
        for (int nt = 0; nt < 4; nt++) {
            const int d = nt * 16 + l15;
#pragma unroll
            for (int r = 0; r < 4; r++) {
                const int e = R0 + l4 * 4 + r;
                outp[(size_t)e * 512 + d] = (bf16)accO[nt][r];
            }
        }
        __syncthreads();
    }
}

// K4s: MLP GEMM. M=65536, N=512, K=512. 2-phase double-buffered like qkv.
// Writes y = att@Wmlp + bmlp as BF16 (residual+LN+pool in K5s; output is a
// masked mean so rounding noise averages down).
__global__ __launch_bounds__(256) void mlp_gemm_kernel(
    const bf16* __restrict__ att, const bf16* __restrict__ Wmlp_t,
    const float* __restrict__ bmlp, bf16* __restrict__ y)
{
    __shared__ __align__(16) bf16 As[2][128 * 64];
    __shared__ __align__(16) bf16 Bs[2][128 * 64];
    const int bid = blockIdx.x;
    const int idx = (bid & 7) * 256 + (bid >> 3);   // XCD swizzle (2048 % 8 == 0)
    const int tm = idx >> 2, tn = idx & 3;
    const int tid = threadIdx.x;
    const int w = tid >> 6, l = tid & 63;
    const int wr = w >> 1, wc = w & 1;
    const int l15 = l & 15, l4 = l >> 4;

    const f32x4 fz = {0.f, 0.f, 0.f, 0.f};
    f32x4 acc[4][4];
#pragma unroll
    for (int m = 0; m < 4; m++)
#pragma unroll
        for (int n = 0; n < 4; n++) acc[m][n] = fz;

    const int arow = l >> 3;
    const int axc = ((l & 7) ^ arow) * 8;
    const bf16* Abase = att + (size_t)(tm * 128) * 512;
    const bf16* Bbase0 = Wmlp_t + (size_t)tn * 8 * 8192;
    const int rsw = (l15 & 7) << 4;

#pragma unroll
    for (int i = 0; i < 4; i++) {
        gld16(Abase + (size_t)((i * 4 + w) * 8 + arow) * 512 + axc,
              As[0] + (i * 4 + w) * 512);
        gld16(Bbase0 + (size_t)((i * 4 + w) * 8 + arow) * 64 + axc,
              Bs[0] + (i * 4 + w) * 512);
    }
    __syncthreads();

    for (int kc = 0; kc < 8; kc++) {
        const int cur = kc & 1;
        if (kc < 7) {
#pragma unroll
            for (int i = 0; i < 4; i++) {
                gld16(Abase + (size_t)((i * 4 + w) * 8 + arow) * 512 + (kc + 1) * 64 + axc,
                      As[cur ^ 1] + (i * 4 + w) * 512);
                gld16(Bbase0 + (size_t)(kc + 1) * 8192 + (size_t)((i * 4 + w) * 8 + arow) * 64 + axc,
                      Bs[cur ^ 1] + (i * 4 + w) * 512);
            }
        }
#pragma unroll
        for (int kk = 0; kk < 2; kk++) {
            const int kb = (kk * 64 + l4 * 16) ^ rsw;
            bf16x8 af[4], bfr[4];
#pragma unroll
            for (int m = 0; m < 4; m++)
                af[m] = *(const bf16x8*)((const char*)As[cur] + (wr * 64 + m * 16 + l15) * 128 + kb);
#pragma unroll
            for (int n = 0; n < 4; n++)
                bfr[n] = *(const bf16x8*)((const char*)Bs[cur] + (wc * 64 + n * 16 + l15) * 128 + kb);
#pragma unroll
            for (int m = 0; m < 4; m++)
#pragma unroll
                for (int n = 0; n < 4; n++)
                    acc[m][n] = mfma16(af[m], bfr[n], acc[m][n]);
        }
        __syncthreads();
    }

    const int colBase = tn * 128 + wc * 64;
    const int mrowBase = tm * 128 + wr * 64;
#pragma unroll
    for (int n = 0; n < 4; n++) {
        int col = colBase + n * 16 + l15;
        float bias = bmlp[col];
#pragma unroll
        for (int m = 0; m < 4; m++) {
            int row0 = mrowBase + m * 16 + l4 * 4;
#pragma unroll
            for (int r = 0; r < 4; r++)
                y[(size_t)(row0 + r) * 512 + col] = (bf16)(acc[m][n][r] + bias);
        }
    }
}

// K5s: per-batch residual + post-LN + masked mean pool (memory-bound).
__global__ __launch_bounds__(512) void pool_kernel(
    const bf16* __restrict__ y, const float* __restrict__ x,
    const float* __restrict__ mask, const float* __restrict__ gpost,
    const float* __restrict__ bpost, float* __restrict__ out)
{
    __shared__ float partial[8][512];
    __shared__ float mrow[128];
    __shared__ float msum_s;

    const int b = blockIdx.x;
    const int tid = threadIdx.x;
    const int w = tid >> 6, l = tid & 63;
    const int k0 = l * 8;

    if (tid < 128) mrow[tid] = mask[b * 128 + tid];
    __syncthreads();
    if (w == 0) {
        float v = mrow[l] + mrow[64 + l];
#pragma unroll
        for (int m = 1; m < 64; m <<= 1) v += __shfl_xor(v, m, 64);
        if (l == 0) msum_s = v;
    }

    f32x4 g0 = *(const f32x4*)(gpost + k0);
    f32x4 g1 = *(const f32x4*)(gpost + k0 + 4);
    f32x4 b0 = *(const f32x4*)(bpost + k0);
    f32x4 b1 = *(const f32x4*)(bpost + k0 + 4);

    f32x4 a0 = {0.f, 0.f, 0.f, 0.f}, a1 = {0.f, 0.f, 0.f, 0.f};
    for (int i = 0; i < 16; i++) {
        int row = w * 16 + i;
        const bf16*  yr = y + ((size_t)(b * 128 + row)) * 512 + k0;
        const float* xr = x + ((size_t)(b * 128 + row)) * 512 + k0;
        bf16x8 yv = *(const bf16x8*)yr;
        f32x4 v0, v1;
#pragma unroll
        for (int j = 0; j < 4; j++) {
            v0[j] = (float)yv[j]     + xr[j];
            v1[j] = (float)yv[j + 4] + xr[j + 4];
        }
        float s = 0.f, ss = 0.f;
#pragma unroll
        for (int j = 0; j < 4; j++) {
            s += v0[j] + v1[j];
            ss += v0[j] * v0[j] + v1[j] * v1[j];
        }
#pragma unroll
        for (int m = 1; m < 64; m <<= 1) {
            s  += __shfl_xor(s, m, 64);
            ss += __shfl_xor(ss, m, 64);
        }
        float mu = s * (1.f / 512.f);
        float rstd = rsqrtf(ss * (1.f / 512.f) - mu * mu + 1e-3f);
        float mr = mrow[row];
#pragma unroll
        for (int j = 0; j < 4; j++) {
            a0[j] += ((v0[j] - mu) * rstd * g0[j] + b0[j]) * mr;
            a1[j] += ((v1[j] - mu) * rstd * g1[j] + b1[j]) * mr;
        }
    }
#pragma unroll
    for (int j = 0; j < 4; j++) {
        partial[w][k0 + j]     = a0[j];
        partial[w][k0 + 4 + j] = a1[j];
    }
    __syncthreads();
    float t = 0.f;
#pragma unroll
    for (int ww = 0; ww < 8; ww++) t += partial[ww][tid];
    out[(size_t)b * 512 + tid] = t / (msum_s + 1e-5f);
}

// ===========================================================================
// FALLBACK PATH — round-1 kernels, verbatim (known-passing).
// ===========================================================================
__global__ __launch_bounds__(256) void prep_kernel(
    const float* __restrict__ Wqk, const float* __restrict__ bqk,
    const float* __restrict__ Wv, const float* __restrict__ bv,
    const float* __restrict__ Wmlp,
    bf16* __restrict__ Wqkv_t, bf16* __restrict__ Wmlp_t, float* __restrict__ bQKV)
{
    int t = blockIdx.x * 256 + threadIdx.x;
    const int NQKV = 8 * 192 * 512;
    if (t < NQKV) {
        int h = t / (192 * 512);
        int rem = t - h * (192 * 512);
        int n = rem >> 9;
        int k = rem & 511;
        float v;
        if (n < 64)       v = Wqk[k * 1024 + h * 128 + n * 2];
        else if (n < 128) v = Wqk[k * 1024 + h * 128 + (n - 64) * 2 + 1];
        else              v = Wv[k * 512 + h * 64 + (n - 128)];
        Wqkv_t[t] = (bf16)v;
    } else {
        int u = t - NQKV;
        if (u < 512 * 512) {
            int col = u >> 9, k = u & 511;
            Wmlp_t[u] = (bf16)Wmlp[k * 512 + col];
        } else {
            int j = u - 512 * 512;
            if (j < 1536) {
                int h = j / 192, n = j - h * 192;
                float v;
                if (n < 64)       v = bqk[h * 128 + n * 2];
                else if (n < 128) v = bqk[h * 128 + (n - 64) * 2 + 1];
                else              v = bv[h * 64 + (n - 128)];
                bQKV[j] = v;
            }
        }
    }
}

__global__ __launch_bounds__(512) void attn_kernel(
    const bf16* __restrict__ inp, const float* __restrict__ mask,
    const bf16* __restrict__ Wqkv_t, const float* __restrict__ bQKV,
    bf16* __restrict__ att)
{
    __shared__ __align__(16) char Qs[128 * 128];
    __shared__ __align__(16) char Ks[128 * 128];
    __shared__ __align__(16) char VTs[64 * 256];
    __shared__ __align__(16) char Ps[128 * 256];
    __shared__ float mrow[128];

    const int bid = blockIdx.x;
    const int b = bid & 511;
    const int h = bid >> 9;
    const int tid = threadIdx.x;
    const int w = tid >> 6, l = tid & 63;
    const int l15 = l & 15, l4 = l >> 4;
    const int R0 = w * 16;

    if (tid < 128) mrow[tid] = mask[b * 128 + tid];

    const bf16* A  = inp + (size_t)(b * 128) * 512;
    const bf16* Wh = Wqkv_t + (size_t)h * 192 * 512;
    const f32x4 fz = {0.f, 0.f, 0.f, 0.f};

    f32x4 acc[12];
#pragma unroll
    for (int n = 0; n < 12; n++) acc[n] = fz;
    const bf16* aptr = A + (size_t)(R0 + l15) * 512 + l4 * 8;
#pragma unroll 4
    for (int ks = 0; ks < 16; ks++) {
        bf16x8 af = *(const bf16x8*)(aptr + ks * 32);
#pragma unroll
        for (int n = 0; n < 12; n++) {
            bf16x8 bfr = *(const bf16x8*)(Wh + (size_t)(n * 16 + l15) * 512 + ks * 32 + l4 * 8);
            acc[n] = mfma16(af, bfr, acc[n]);
        }
    }
#pragma unroll
    for (int n = 0; n < 12; n++) {
        int col = n * 16 + l15;
        float bias = bQKV[h * 192 + col];
#pragma unroll
        for (int r = 0; r < 4; r++) {
            int row = R0 + l4 * 4 + r;
            bf16 val = (bf16)(acc[n][r] + bias);
            if (n < 4) {
                *(bf16*)(Qs + row * 128 + SWZ(col * 2, row)) = val;
            } else if (n < 8) {
                *(bf16*)(Ks + row * 128 + SWZ((col - 64) * 2, row)) = val;
            } else {
                int d = col - 128;
                *(bf16*)(VTs + d * 256 + SWZ(row * 2, d)) = val;
            }
        }
    }
    __syncthreads();

    f32x4 accL[8];
#pragma unroll
    for (int n = 0; n < 8; n++) accL[n] = fz;
#pragma unroll
    for (int ks = 0; ks < 2; ks++) {
        int k = ks * 32 + l4 * 8;
        int qrow = R0 + l15;
        bf16x8 af = *(const bf16x8*)(Qs + qrow * 128 + SWZ(k * 2, qrow));
#pragma unroll
        for (int nt = 0; nt < 8; nt++) {
            int krow = nt * 16 + l15;
            bf16x8 bfr = *(const bf16x8*)(Ks + krow * 128 + SWZ(k * 2, krow));
            accL[nt] = mfma16(af, bfr, accL[nt]);
        }
    }
    float pv[32];
#pragma unroll
    for (int r = 0; r < 4; r++) {
        float mx = -1e30f;
#pragma unroll
        for (int nt = 0; nt < 8; nt++) {
            int colk = nt * 16 + l15;
            float v = accL[nt][r] * 0.125f - (1.0f - mrow[colk]) * 1e10f;
            pv[nt * 4 + r] = v;
            mx = fmaxf(mx, v);
        }
#pragma unroll
        for (int m = 1; m < 16; m <<= 1) mx = fmaxf(mx, __shfl_xor(mx, m, 64));
        float sum = 0.f;
#pragma unroll
        for (int nt = 0; nt < 8; nt++) {
            int colk = nt * 16 + l15;
            float e = __expf(pv[nt * 4 + r] - mx) * mrow[colk];
            pv[nt * 4 + r] = e;
            sum += e;
        }
#pragma unroll
        for (int m = 1; m < 16; m <<= 1) sum += __shfl_xor(sum, m, 64);
        float inv = 1.0f / (sum + 1e-10f);
        int prow = R0 + l4 * 4 + r;
#pragma unroll
        for (int nt = 0; nt < 8; nt++) {
            bf16 pb = (bf16)(pv[nt * 4 + r] * inv);
            *(bf16*)(Ps + prow * 256 + SWZ((nt * 16 + l15) * 2, prow)) = pb;
        }
    }
    __syncthreads();

    f32x4 accO[4];
#pragma unroll
    for (int n = 0; n < 4; n++) accO[n] = fz;
#pragma unroll
    for (int ks = 0; ks < 4; ks++) {
        int k = ks * 32 + l4 * 8;
        int prow = R0 + l15;
        bf16x8 af = *(const bf16x8*)(Ps + prow * 256 + SWZ(k * 2, prow));
#pragma unroll
        for (int nt = 0; nt < 4; nt++) {
            int d = nt * 16 + l15;
            bf16x8 bfr = *(const bf16x8*)(VTs + d * 256 + SWZ(k * 2, d));
            accO[nt] = mfma16(af, bfr, accO[nt]);
        }
    }
    bf16* outp = att + (size_t)(b * 128) * 512 + h * 64;
#pragma unroll
    for (int nt = 0; nt < 4; nt++) {
        int d = nt * 16 + l15;
#pragma unroll
        for (int r = 0; r < 4; r++) {
            int e = R0 + l4 * 4 + r;
            outp[(size_t)e * 512 + d] = (bf16)accO[nt][r];
        }
    }
}

__global__ __launch_bounds__(512) void mlp_kernel(
    const bf16* __restrict__ att, const bf16* __restrict__ Wmlp_t,
    const float* __restrict__ bmlp, const float* __restrict__ x,
    const float* __restrict__ mask, const float* __restrict__ gpost,
    const float* __restrict__ bpost, float* __restrict__ out)
{
    __shared__ float pool[512];
    __shared__ float gb[1024];
    __shared__ float mrow[128];
    __shared__ float msum_s;

    const int b = blockIdx.x;
    const int tid = threadIdx.x;
    const int w = tid >> 6, l = tid & 63;
    const int l15 = l & 15, l4 = l >> 4;
    const int R0 = w * 16;

    pool[tid] = 0.f;
    gb[tid] = gpost[tid];
    gb[512 + tid] = bpost[tid];
    if (tid < 128) mrow[tid] = mask[b * 128 + tid];
    __syncthreads();
    if (w == 0) {
        float v = mrow[l] + mrow[64 + l];
#pragma unroll
        for (int m = 1; m < 64; m <<= 1) v += __shfl_xor(v, m, 64);
        if (l == 0) msum_s = v;
    }

    const f32x4 fz = {0.f, 0.f, 0.f, 0.f};
    f32x4 acc[32];
#pragma unroll
    for (int n = 0; n < 32; n++) acc[n] = fz;
    const bf16* Ab = att + (size_t)(b * 128 + R0 + l15) * 512 + l4 * 8;
#pragma unroll 2
    for (int ks = 0; ks < 16; ks++) {
        bf16x8 af = *(const bf16x8*)(Ab + ks * 32);
#pragma unroll
        for (int nt = 0; nt < 32; nt++) {
            bf16x8 bfr = *(const bf16x8*)(Wmlp_t + (size_t)(nt * 16 + l15) * 512 + ks * 32 + l4 * 8);
            acc[nt] = mfma16(af, bfr, acc[nt]);
        }
    }
#pragma unroll
    for (int nt = 0; nt < 32; nt++) {
        int col = nt * 16 + l15;
        float bb = bmlp[col];
#pragma unroll
        for (int r = 0; r < 4; r++) {
            int row = R0 + l4 * 4 + r;
            acc[nt][r] = acc[nt][r] + bb + x[((size_t)b * 128 + row) * 512 + col];
        }
    }
    float mu[4], rs[4];
#pragma unroll
    for (int r = 0; r < 4; r++) {
        float s = 0.f, ss = 0.f;
#pragma unroll
        for (int nt = 0; nt < 32; nt++) {
            float v = acc[nt][r];
            s += v; ss += v * v;
        }
#pragma unroll
        for (int m = 1; m < 16; m <<= 1) {
            s  += __shfl_xor(s, m, 64);
            ss += __shfl_xor(ss, m, 64);
        }
        float m_ = s * (1.f / 512.f);
        mu[r] = m_;
        rs[r] = rsqrtf(ss * (1.f / 512.f) - m_ * m_ + 1e-3f);
    }
#pragma unroll
    for (int nt = 0; nt < 32; nt++) {
        int col = nt * 16 + l15;
        float g = gb[col], bb = gb[512 + col];
        float s = 0.f;
#pragma unroll
        for (int r = 0; r < 4; r++) {
            int row = R0 + l4 * 4 + r;
            float y = (acc[nt][r] - mu[r]) * rs[r] * g + bb;
            s += y * mrow[row];
        }
        atomicAdd(&pool[col], s);
    }
    __syncthreads();
    out[(size_t)b * 512 + tid] = pool[tid] / (msum_s + 1e-5f);
}

// ---------------------------------------------------------------------------
extern "C" void kernel_launch(void* const* d_in, const int* in_sizes, int n_in,
                              void* d_out, int out_size, void* d_ws, size_t ws_size,
                              hipStream_t stream)
{
    const float* x     = (const float*)d_in[0];
    const float* mask  = (const float*)d_in[1];
    const float* Wqk   = (const float*)d_in[2];
    const float* bqk   = (const float*)d_in[3];
    const float* Wv    = (const float*)d_in[4];
    const float* bv    = (const float*)d_in[5];
    const float* Wmlp  = (const float*)d_in[6];
    const float* bmlp  = (const float*)d_in[7];
    const float* gpre  = (const float*)d_in[8];
    const float* bpre  = (const float*)d_in[9];
    const float* gpost = (const float*)d_in[10];
    const float* bpost = (const float*)d_in[11];
    float* out = (float*)d_out;
    char* ws = (char*)d_ws;

    const size_t NEED_SPLIT = 270538752;   // 256MiB buffers + 2MiB weights + 6KiB bias
    if (ws_size >= NEED_SPLIT) {
        bf16*  q      = (bf16*)ws;                               // 64 MiB
        bf16*  kbuf   = (bf16*)(ws + (size_t)67108864);          // 64 MiB
        bf16*  vt     = (bf16*)(ws + (size_t)134217728);         // 64 MiB
        bf16*  inp    = (bf16*)(ws + (size_t)201326592);         // 64 MiB (att aliases)
        bf16*  att    = inp;
        bf16*  y      = (bf16*)ws;                               // 64 MiB, aliases q (dead)
        bf16*  Wqkv_s = (bf16*)(ws + (size_t)268435456);         // 1.5 MiB
        bf16*  Wmlp_t = (bf16*)(ws + (size_t)270008320);         // 0.5 MiB
        float* bQKV   = (float*)(ws + (size_t)270532608);        // 6 KiB

        prep_split_kernel<<<4103, 256, 0, stream>>>(Wqk, bqk, Wv, bv, Wmlp, Wqkv_s, Wmlp_t, bQKV);
        ln_kernel<<<16384, 256, 0, stream>>>(x, gpre, bpre, inp);
        qkv_gemm_kernel<<<6144, 256, 0, stream>>>(inp, Wqkv_s, bQKV, q, kbuf, vt);
        attn_fused_kernel<<<512, 512, 0, stream>>>(q, kbuf, vt, mask, att);
        mlp_gemm_kernel<<<2048, 256, 0, stream>>>(att, Wmlp_t, bmlp, y);
        pool_kernel<<<512, 512, 0, stream>>>(y, x, mask, gpost, bpost, out);
    } else {
        bf16*  inp    = (bf16*)ws;                                   // 64 MiB
        bf16*  att    = (bf16*)(ws + 67108864);                      // 64 MiB
        bf16*  Wqkv_t = (bf16*)(ws + 134217728);                     // 1.5 MiB
        bf16*  Wmlp_t = (bf16*)(ws + 134217728 + 1572864);           // 0.5 MiB
        float* bQKV   = (float*)(ws + 134217728 + 1572864 + 524288); // 6 KiB

        prep_kernel<<<4103, 256, 0, stream>>>(Wqk, bqk, Wv, bv, Wmlp, Wqkv_t, Wmlp_t, bQKV);
        ln_kernel<<<16384, 256, 0, stream>>>(x, gpre, bpre, inp);
        attn_kernel<<<4096, 512, 0, stream>>>(inp, mask, Wqkv_t, bQKV, att);
        mlp_kernel<<<512, 512, 0, stream>>>(att, Wmlp_t, bmlp, x, mask, gpost, bpost, out);
    }
}

// Round 9
// 528.948 us; speedup vs baseline: 1.0660x; 1.0071x over previous
//
#include <hip/hip_runtime.h>
#include <hip/hip_bf16.h>

// ---------------------------------------------------------------------------
// Transformer block: pre-LN -> QKV GEMM -> masked softmax attention -> MLP ->
// residual -> post-LN -> masked mean pool.
// bs=512, NE=128, F=512, heads=8, d=64. GEMMs in bf16 MFMA 16x16x32.
// Split path (ws >= 258MB): ln -> qkv_gemm (8-wave 128x128 tile, 2-phase
//   dbuf LDS, 4 waves/SIMD) -> attn_fused -> mlp_gemm (same) -> pool.
// Fallback path (small ws): round-1 fused kernels (known-passing).
// ---------------------------------------------------------------------------

typedef __bf16 bf16;
typedef __bf16 bf16x8 __attribute__((ext_vector_type(8)));
typedef __bf16 bf16x4 __attribute__((ext_vector_type(4)));
typedef float f32x4 __attribute__((ext_vector_type(4)));
typedef unsigned u32x4 __attribute__((ext_vector_type(4)));

__device__ __forceinline__ f32x4 mfma16(bf16x8 a, bf16x8 b, f32x4 c) {
    return __builtin_amdgcn_mfma_f32_16x16x32_bf16(a, b, c, 0, 0, 0);
}

// async global->LDS copy, 16B per lane. LDS dest = wave-uniform base + lane*16.
typedef const unsigned int __attribute__((address_space(1)))* gptr_t;
typedef unsigned int __attribute__((address_space(3)))* lptr_t;
__device__ __forceinline__ void gld16(const void* g, void* l) {
    __builtin_amdgcn_global_load_lds((gptr_t)g, (lptr_t)l, 16, 0, 0);
}

__device__ __forceinline__ unsigned pack2(float lo, float hi) {
    unsigned short a = __builtin_bit_cast(unsigned short, (bf16)lo);
    unsigned short b = __builtin_bit_cast(unsigned short, (bf16)hi);
    return (unsigned)a | ((unsigned)b << 16);
}

#define SWZ(byteoff, row) ((byteoff) ^ (((row) & 7) << 4))

// ===========================================================================
// SPLIT PATH
// ===========================================================================

// K0s: weight prep, OUTPUT-indexed (lane-contiguous writes).
__global__ __launch_bounds__(256) void prep_split_kernel(
    const float* __restrict__ Wqk, const float* __restrict__ bqk,
    const float* __restrict__ Wv, const float* __restrict__ bv,
    const float* __restrict__ Wmlp,
    bf16* __restrict__ Wqkv_s, bf16* __restrict__ Wmlp_t, float* __restrict__ bQKV)
{
    int t = blockIdx.x * 256 + threadIdx.x;
    if (t < 786432) {                        // Wqkv_s outputs
        int tnkc = t >> 13;                  // (tn*8+kc), 0..95
        int within = t & 8191;
        int nc = within >> 6, kw = within & 63;
        int tn = tnkc >> 3, kc = tnkc & 7;
        int n = tn * 128 + nc, k = kc * 64 + kw;
        float v;
        if (n < 512)       v = Wqk[k * 1024 + (n >> 6) * 128 + (n & 63) * 2];
        else if (n < 1024) { int nn = n - 512;
                             v = Wqk[k * 1024 + (nn >> 6) * 128 + (nn & 63) * 2 + 1]; }
        else               v = Wv[k * 512 + (n - 1024)];
        Wqkv_s[t] = (bf16)v;
    } else if (t < 1048576) {                // Wmlp_t outputs
        int u = t - 786432;
        int tnkc = u >> 13;                  // 0..31
        int within = u & 8191;
        int nc = within >> 6, kw = within & 63;
        int tn = tnkc >> 3, kc = tnkc & 7;
        int n = tn * 128 + nc, k = kc * 64 + kw;
        Wmlp_t[u] = (bf16)Wmlp[k * 512 + n];
    } else if (t < 1050112) {                // biases
        int j = t - 1048576;
        int region = j >> 9, w9 = j & 511, h = w9 >> 6, d = w9 & 63;
        float v;
        if (region == 0)      v = bqk[h * 128 + d * 2];
        else if (region == 1) v = bqk[h * 128 + d * 2 + 1];
        else                  v = bv[h * 64 + d];
        bQKV[j] = v;
    }
}

// K1: pre-LN + cast to bf16. One wave per row of 512.
__global__ __launch_bounds__(256) void ln_kernel(
    const float* __restrict__ x, const float* __restrict__ g,
    const float* __restrict__ b, bf16* __restrict__ inp)
{
    int row = blockIdx.x * 4 + (threadIdx.x >> 6);
    int lane = threadIdx.x & 63;
    int k0 = lane * 8;
    const float* xr = x + (size_t)row * 512 + k0;
    f32x4 a0 = *(const f32x4*)xr;
    f32x4 a1 = *(const f32x4*)(xr + 4);
    float s = 0.f, ss = 0.f;
#pragma unroll
    for (int i = 0; i < 4; i++) {
        s += a0[i] + a1[i];
        ss += a0[i] * a0[i] + a1[i] * a1[i];
    }
#pragma unroll
    for (int m = 1; m < 64; m <<= 1) {
        s  += __shfl_xor(s, m, 64);
        ss += __shfl_xor(ss, m, 64);
    }
    float mu = s * (1.f / 512.f);
    float rstd = rsqrtf(ss * (1.f / 512.f) - mu * mu + 1e-3f);
    f32x4 g0 = *(const f32x4*)(g + k0);
    f32x4 g1 = *(const f32x4*)(g + k0 + 4);
    f32x4 b0 = *(const f32x4*)(b + k0);
    f32x4 b1 = *(const f32x4*)(b + k0 + 4);
    bf16x8 ov;
#pragma unroll
    for (int i = 0; i < 4; i++) {
        ov[i]     = (bf16)((a0[i] - mu) * rstd * g0[i] + b0[i]);
        ov[i + 4] = (bf16)((a1[i] - mu) * rstd * g1[i] + b1[i]);
    }
    *(bf16x8*)(inp + (size_t)row * 512 + k0) = ov;
}

// K2s: QKV GEMM. M=65536, N=1536, K=512. 128x128 tile, 8 waves (2x4 grid,
// wave-tile 64x32), BK=64, 2-phase double-buffered LDS, XOR-swizzled.
// 512 threads -> 2 blocks/CU -> 16 waves/CU = 4/SIMD (2x latency hiding
// vs the 4-wave version; occupancy was the binding constraint).
__global__ __launch_bounds__(512) void qkv_gemm_kernel(
    const bf16* __restrict__ inp, const bf16* __restrict__ Wqkv_s,
    const float* __restrict__ bQKV,
    bf16* __restrict__ q, bf16* __restrict__ kbuf, bf16* __restrict__ vt)
{
    __shared__ __align__(16) bf16 As[2][128 * 64];
    __shared__ __align__(16) bf16 Bs[2][128 * 64];
    const int bid = blockIdx.x;
    const int idx = (bid & 7) * 768 + (bid >> 3);   // XCD swizzle (6144 % 8 == 0)
    const int tm = idx / 12, tn = idx % 12;
    const int tid = threadIdx.x;
    const int w = tid >> 6, l = tid & 63;
    const int wr = w >> 2, wc = w & 3;              // 2x4 wave grid
    const int l15 = l & 15, l4 = l >> 4;

    const f32x4 fz = {0.f, 0.f, 0.f, 0.f};
    f32x4 acc[4][2];
#pragma unroll
    for (int m = 0; m < 4; m++)
#pragma unroll
        for (int n = 0; n < 2; n++) acc[m][n] = fz;

    const int arow = l >> 3;                         // 0..7 (== LDS row & 7)
    const int axc = ((l & 7) ^ arow) * 8;            // inverse-swizzled col
    const bf16* Abase = inp + (size_t)(tm * 128) * 512;
    const bf16* Bbase0 = Wqkv_s + (size_t)tn * 8 * 8192;
    const int rsw = (l15 & 7) << 4;                  // read-side XOR (bytes)

    // prologue: stage kc=0 into buf 0 (2 issues/wave for A, 2 for B)
#pragma unroll
    for (int i = 0; i < 2; i++) {
        gld16(Abase + (size_t)((i * 8 + w) * 8 + arow) * 512 + axc,
              As[0] + (i * 8 + w) * 512);
        gld16(Bbase0 + (size_t)((i * 8 + w) * 8 + arow) * 64 + axc,
              Bs[0] + (i * 8 + w) * 512);
    }
    __syncthreads();

    for (int kc = 0; kc < 8; kc++) {
        const int cur = kc & 1;
        if (kc < 7) {                                // issue next-tile stage first
#pragma unroll
            for (int i = 0; i < 2; i++) {
                gld16(Abase + (size_t)((i * 8 + w) * 8 + arow) * 512 + (kc + 1) * 64 + axc,
                      As[cur ^ 1] + (i * 8 + w) * 512);
                gld16(Bbase0 + (size_t)(kc + 1) * 8192 + (size_t)((i * 8 + w) * 8 + arow) * 64 + axc,
                      Bs[cur ^ 1] + (i * 8 + w) * 512);
            }
        }
#pragma unroll
        for (int kk = 0; kk < 2; kk++) {
            const int kb = (kk * 64 + l4 * 16) ^ rsw;  // swizzled byte offset
            bf16x8 af[4], bfr[2];
#pragma unroll
            for (int m = 0; m < 4; m++)
                af[m] = *(const bf16x8*)((const char*)As[cur] + (wr * 64 + m * 16 + l15) * 128 + kb);
#pragma unroll
            for (int n = 0; n < 2; n++)
                bfr[n] = *(const bf16x8*)((const char*)Bs[cur] + (wc * 32 + n * 16 + l15) * 128 + kb);
#pragma unroll
            for (int m = 0; m < 4; m++)
#pragma unroll
                for (int n = 0; n < 2; n++)
                    acc[m][n] = mfma16(af[m], bfr[n], acc[m][n]);
        }
        __syncthreads();   // drains this wave's stage loads; swap buffers
    }

    const int colBase = tn * 128 + wc * 32;
    const int mrowBase = tm * 128 + wr * 64;
#pragma unroll
    for (int n = 0; n < 2; n++) {
        int col = colBase + n * 16 + l15;
        float bias = bQKV[col];
        int within = col & 511, hh = within >> 6, dd = within & 63;
#pragma unroll
        for (int m = 0; m < 4; m++) {
            int mr0 = mrowBase + m * 16 + l4 * 4;
            int bb = mr0 >> 7, e0 = mr0 & 127;
            size_t base = (size_t)(bb * 8 + hh) * 8192;
            if (tn < 4) {
#pragma unroll
                for (int r = 0; r < 4; r++)
                    q[base + (size_t)(e0 + r) * 64 + dd] = (bf16)(acc[m][n][r] + bias);
            } else if (tn < 8) {
#pragma unroll
                for (int r = 0; r < 4; r++) {
                    int e = e0 + r;
                    kbuf[base + (size_t)e * 64 + (dd ^ ((e & 7) << 3))] = (bf16)(acc[m][n][r] + bias);
                }
            } else {
                bf16x4 pk;
#pragma unroll
                for (int r = 0; r < 4; r++) pk[r] = (bf16)(acc[m][n][r] + bias);
                *(bf16x4*)(vt + base + (size_t)dd * 128 + (e0 ^ ((dd & 7) << 3))) = pk;
            }
        }
    }
}

// K3s: fused attention, one block per batch, 8-head loop, double-buffered
// K/V staging, swapped QK^T + in-register softmax + in-register P transpose.
__global__ __launch_bounds__(512) void attn_fused_kernel(
    const bf16* __restrict__ q, const bf16* __restrict__ kbuf,
    const bf16* __restrict__ vt, const float* __restrict__ mask,
    bf16* __restrict__ att)
{
    __shared__ __align__(16) char Ks[2][128 * 128];   // [buf][krow][64d] swizzled
    __shared__ __align__(16) char VTs[2][64 * 256];   // [buf][d][128e] swizzled
    __shared__ float mrow[128];

    const int b = blockIdx.x;
    const size_t bh0 = (size_t)b * 8;
    const int tid = threadIdx.x;
    const int w = tid >> 6, l = tid & 63;
    const int l15 = l & 15, l4 = l >> 4, R0 = w * 16;

    if (tid < 128) mrow[tid] = mask[b * 128 + tid];

    {
        const bf16* kb = kbuf + bh0 * 8192;
        const bf16* vb = vt + bh0 * 8192;
#pragma unroll
        for (int i = 0; i < 2; i++) {
            gld16(kb + ((i * 8 + w) * 64 + l) * 8, (bf16*)Ks[0] + (i * 8 + w) * 512);
            gld16(vb + ((i * 8 + w) * 64 + l) * 8, (bf16*)VTs[0] + (i * 8 + w) * 512);
        }
    }
    const bf16* qp0 = q + bh0 * 8192 + (size_t)(R0 + l15) * 64 + l4 * 8;
    bf16x8 afn0 = *(const bf16x8*)(qp0);
    bf16x8 afn1 = *(const bf16x8*)(qp0 + 32);
    __syncthreads();

    const f32x4 fz = {0.f, 0.f, 0.f, 0.f};
    for (int h = 0; h < 8; h++) {
        const int cur = h & 1;
        bf16x8 af0 = afn0, af1 = afn1;
        if (h < 7) {
            const bf16* kb = kbuf + (bh0 + h + 1) * 8192;
            const bf16* vb = vt + (bh0 + h + 1) * 8192;
#pragma unroll
            for (int i = 0; i < 2; i++) {
                gld16(kb + ((i * 8 + w) * 64 + l) * 8, (bf16*)Ks[cur ^ 1] + (i * 8 + w) * 512);
                gld16(vb + ((i * 8 + w) * 64 + l) * 8, (bf16*)VTs[cur ^ 1] + (i * 8 + w) * 512);
            }
            const bf16* qp = q + (bh0 + h + 1) * 8192 + (size_t)(R0 + l15) * 64 + l4 * 8;
            afn0 = *(const bf16x8*)(qp);
            afn1 = *(const bf16x8*)(qp + 32);
        }

        // swapped QK^T: accL[nt][r] = S[q=R0+l15][k=nt*16+l4*4+r]
        f32x4 accL[8];
#pragma unroll
        for (int n = 0; n < 8; n++) accL[n] = fz;
#pragma unroll
        for (int ks = 0; ks < 2; ks++) {
            bf16x8 bq = ks ? af1 : af0;
            const int k2 = ks * 64 + l4 * 16;
#pragma unroll
            for (int nt = 0; nt < 8; nt++) {
                const int krow = nt * 16 + l15;
                bf16x8 kf = *(const bf16x8*)(Ks[cur] + krow * 128 + (k2 ^ ((krow & 7) << 4)));
                accL[nt] = mfma16(kf, bq, accL[nt]);
            }
        }

        // masked softmax along k (lane-local 32 vals + xor16/32 reduce)
        float mx = -1e30f;
#pragma unroll
        for (int nt = 0; nt < 8; nt++)
#pragma unroll
            for (int r = 0; r < 4; r++) {
                float mk = mrow[nt * 16 + l4 * 4 + r];
                float v = accL[nt][r] * 0.125f - (1.0f - mk) * 1e10f;
                accL[nt][r] = v;
                mx = fmaxf(mx, v);
            }
        mx = fmaxf(mx, __shfl_xor(mx, 16, 64));
        mx = fmaxf(mx, __shfl_xor(mx, 32, 64));
        float sum = 0.f;
#pragma unroll
        for (int nt = 0; nt < 8; nt++)
#pragma unroll
            for (int r = 0; r < 4; r++) {
                float mk = mrow[nt * 16 + l4 * 4 + r];
                float e = __expf(accL[nt][r] - mx) * mk;
                accL[nt][r] = e;
                sum += e;
            }
        sum += __shfl_xor(sum, 16, 64);
        sum += __shfl_xor(sum, 32, 64);
        const float inv = 1.0f / (sum + 1e-10f);

        unsigned pk[8][2];
#pragma unroll
        for (int nt = 0; nt < 8; nt++)
#pragma unroll
            for (int qq = 0; qq < 2; qq++)
                pk[nt][qq] = pack2(accL[nt][2 * qq] * inv, accL[nt][2 * qq + 1] * inv);

        // PV: in-register P transpose -> A-fragments, B from VTs LDS
        f32x4 accO[4];
#pragma unroll
        for (int n = 0; n < 4; n++) accO[n] = fz;
        const int glo = l15 + ((l4 & 1) << 5);
#pragma unroll
        for (int ks = 0; ks < 4; ks++) {
            u32x4 pa4;
#pragma unroll
            for (int p = 0; p < 4; p++) {
                int srcl = glo + ((p >> 1) << 4);
                unsigned va = (unsigned)__shfl((int)pk[2 * ks][p & 1], srcl, 64);
                unsigned vb = (unsigned)__shfl((int)pk[2 * ks + 1][p & 1], srcl, 64);
                pa4[p] = (l4 & 2) ? vb : va;
            }
            bf16x8 pa = __builtin_bit_cast(bf16x8, pa4);
            const int e2 = ks * 64 + l4 * 16;
#pragma unroll
            for (int nt = 0; nt < 4; nt++) {
                const int d = nt * 16 + l15;
                bf16x8 vf = *(const bf16x8*)(VTs[cur] + d * 256 + (e2 ^ ((d & 7) << 4)));
                accO[nt] = mfma16(pa, vf, accO[nt]);
            }
        }

        bf16* outp = att + (size_t)(b * 128) * 512 + h * 64;
#pragma unroll
        for (int nt = 0; nt < 4; nt++) {
            const int d = nt * 16 + l15;
#pragma unroll
            for (int r = 0; r < 4; r++) {
                const int e = R0 + l4 * 4 + r;
                outp[(size_t)e * 512 + d] = (bf16)accO[nt][r];
            }
        }
        __syncthreads();
    }
}

// K4s: MLP GEMM. M=65536, N=512, K=512. 8-wave 128x128 tile like qkv.
// Writes y = att@Wmlp + bmlp as BF16.
__global__ __launch_bounds__(512) void mlp_gemm_kernel(
    const bf16* __restrict__ att, const bf16* __restrict__ Wmlp_t,
    const float* __restrict__ bmlp, bf16* __restrict__ y)
{
    __shared__ __align__(16) bf16 As[2][128 * 64];
    __shared__ __align__(16) bf16 Bs[2][128 * 64];
    const int bid = blockIdx.x;
    const int idx = (bid & 7) * 256 + (bid >> 3);   // XCD swizzle (2048 % 8 == 0)
    const int tm = idx >> 2, tn = idx & 3;
    const int tid = threadIdx.x;
    const int w = tid >> 6, l = tid & 63;
    const int wr = w >> 2, wc = w & 3;              // 2x4 wave grid
    const int l15 = l & 15, l4 = l >> 4;

    const f32x4 fz = {0.f, 0.f, 0.f, 0.f};
    f32x4 acc[4][2];
#pragma unroll
    for (int m = 0; m < 4; m++)
#pragma unroll
        for (int n = 0; n < 2; n++) acc[m][n] = fz;

    const int arow = l >> 3;
    const int axc = ((l & 7) ^ arow) * 8;
    const bf16* Abase = att + (size_t)(tm * 128) * 512;
    const bf16* Bbase0 = Wmlp_t + (size_t)tn * 8 * 8192;
    const int rsw = (l15 & 7) << 4;

#pragma unroll
    for (int i = 0; i < 2; i++) {
        gld16(Abase + (size_t)((i * 8 + w) * 8 + arow) * 512 + axc,
              As[0] + (i * 8 + w) * 512);
        gld16(Bbase0 + (size_t)((i * 8 + w) * 8 + arow) * 64 + axc,
              Bs[0] + (i * 8 + w) * 512);
    }
    __syncthreads();

    for (int kc = 0; kc < 8; kc++) {
        const int cur = kc & 1;
        if (kc < 7) {
#pragma unroll
            for (int i = 0; i < 2; i++) {
                gld16(Abase + (size_t)((i * 8 + w) * 8 + arow) * 512 + (kc + 1) * 64 + axc,
                      As[cur ^ 1] + (i * 8 + w) * 512);
                gld16(Bbase0 + (size_t)(kc + 1) * 8192 + (size_t)((i * 8 + w) * 8 + arow) * 64 + axc,
                      Bs[cur ^ 1] + (i * 8 + w) * 512);
            }
        }
#pragma unroll
        for (int kk = 0; kk < 2; kk++) {
            const int kb = (kk * 64 + l4 * 16) ^ rsw;
            bf16x8 af[4], bfr[2];
#pragma unroll
            for (int m = 0; m < 4; m++)
                af[m] = *(const bf16x8*)((const char*)As[cur] + (wr * 64 + m * 16 + l15) * 128 + kb);
#pragma unroll
            for (int n = 0; n < 2; n++)
                bfr[n] = *(const bf16x8*)((const char*)Bs[cur] + (wc * 32 + n * 16 + l15) * 128 + kb);
#pragma unroll
            for (int m = 0; m < 4; m++)
#pragma unroll
                for (int n = 0; n < 2; n++)
                    acc[m][n] = mfma16(af[m], bfr[n], acc[m][n]);
        }
        __syncthreads();
    }

    const int colBase = tn * 128 + wc * 32;
    const int mrowBase = tm * 128 + wr * 64;
#pragma unroll
    for (int n = 0; n < 2; n++) {
        int col = colBase + n * 16 + l15;
        float bias = bmlp[col];
#pragma unroll
        for (int m = 0; m < 4; m++) {
            int row0 = mrowBase + m * 16 + l4 * 4;
#pragma unroll
            for (int r = 0; r < 4; r++)
                y[(size_t)(row0 + r) * 512 + col] = (bf16)(acc[m][n][r] + bias);
        }
    }
}

// K5s: per-batch residual + post-LN + masked mean pool (memory-bound).
__global__ __launch_bounds__(512) void pool_kernel(
    const bf16* __restrict__ y, const float* __restrict__ x,
    const float* __restrict__ mask, const float* __restrict__ gpost,
    const float* __restrict__ bpost, float* __restrict__ out)
{
    __shared__ float partial[8][512];
    __shared__ float mrow[128];
    __shared__ float msum_s;

    const int b = blockIdx.x;
    const int tid = threadIdx.x;
    const int w = tid >> 6, l = tid & 63;
    const int k0 = l * 8;

    if (tid < 128) mrow[tid] = mask[b * 128 + tid];
    __syncthreads();
    if (w == 0) {
        float v = mrow[l] + mrow[64 + l];
#pragma unroll
        for (int m = 1; m < 64; m <<= 1) v += __shfl_xor(v, m, 64);
        if (l == 0) msum_s = v;
    }

    f32x4 g0 = *(const f32x4*)(gpost + k0);
    f32x4 g1 = *(const f32x4*)(gpost + k0 + 4);
    f32x4 b0 = *(const f32x4*)(bpost + k0);
    f32x4 b1 = *(const f32x4*)(bpost + k0 + 4);

    f32x4 a0 = {0.f, 0.f, 0.f, 0.f}, a1 = {0.f, 0.f, 0.f, 0.f};
    for (int i = 0; i < 16; i++) {
        int row = w * 16 + i;
        const bf16*  yr = y + ((size_t)(b * 128 + row)) * 512 + k0;
        const float* xr = x + ((size_t)(b * 128 + row)) * 512 + k0;
        bf16x8 yv = *(const bf16x8*)yr;
        f32x4 v0, v1;
#pragma unroll
        for (int j = 0; j < 4; j++) {
            v0[j] = (float)yv[j]     + xr[j];
            v1[j] = (float)yv[j + 4] + xr[j + 4];
        }
        float s = 0.f, ss = 0.f;
#pragma unroll
        for (int j = 0; j < 4; j++) {
            s += v0[j] + v1[j];
            ss += v0[j] * v0[j] + v1[j] * v1[j];
        }
#pragma unroll
        for (int m = 1; m < 64; m <<= 1) {
            s  += __shfl_xor(s, m, 64);
            ss += __shfl_xor(ss, m, 64);
        }
        float mu = s * (1.f / 512.f);
        float rstd = rsqrtf(ss * (1.f / 512.f) - mu * mu + 1e-3f);
        float mr = mrow[row];
#pragma unroll
        for (int j = 0; j < 4; j++) {
            a0[j] += ((v0[j] - mu) * rstd * g0[j] + b0[j]) * mr;
            a1[j] += ((v1[j] - mu) * rstd * g1[j] + b1[j]) * mr;
        }
    }
#pragma unroll
    for (int j = 0; j < 4; j++) {
        partial[w][k0 + j]     = a0[j];
        partial[w][k0 + 4 + j] = a1[j];
    }
    __syncthreads();
    float t = 0.f;
#pragma unroll
    for (int ww = 0; ww < 8; ww++) t += partial[ww][tid];
    out[(size_t)b * 512 + tid] = t / (msum_s + 1e-5f);
}

// ===========================================================================
// FALLBACK PATH — round-1 kernels, verbatim (known-passing).
// ===========================================================================
__global__ __launch_bounds__(256) void prep_kernel(
    const float* __restrict__ Wqk, const float* __restrict__ bqk,
    const float* __restrict__ Wv, const float* __restrict__ bv,
    const float* __restrict__ Wmlp,
    bf16* __restrict__ Wqkv_t, bf16* __restrict__ Wmlp_t, float* __restrict__ bQKV)
{
    int t = blockIdx.x * 256 + threadIdx.x;
    const int NQKV = 8 * 192 * 512;
    if (t < NQKV) {
        int h = t / (192 * 512);
        int rem = t - h * (192 * 512);
        int n = rem >> 9;
        int k = rem & 511;
        float v;
        if (n < 64)       v = Wqk[k * 1024 + h * 128 + n * 2];
        else if (n < 128) v = Wqk[k * 1024 + h * 128 + (n - 64) * 2 + 1];
        else              v = Wv[k * 512 + h * 64 + (n - 128)];
        Wqkv_t[t] = (bf16)v;
    } else {
        int u = t - NQKV;
        if (u < 512 * 512) {
            int col = u >> 9, k = u & 511;
            Wmlp_t[u] = (bf16)Wmlp[k * 512 + col];
        } else {
            int j = u - 512 * 512;
            if (j < 1536) {
                int h = j / 192, n = j - h * 192;
                float v;
                if (n < 64)       v = bqk[h * 128 + n * 2];
                else if (n < 128) v = bqk[h * 128 + (n - 64) * 2 + 1];
                else              v = bv[h * 64 + (n - 128)];
                bQKV[j] = v;
            }
        }
    }
}

__global__ __launch_bounds__(512) void attn_kernel(
    const bf16* __restrict__ inp, const float* __restrict__ mask,
    const bf16* __restrict__ Wqkv_t, const float* __restrict__ bQKV,
    bf16* __restrict__ att)
{
    __shared__ __align__(16) char Qs[128 * 128];
    __shared__ __align__(16) char Ks[128 * 128];
    __shared__ __align__(16) char VTs[64 * 256];
    __shared__ __align__(16) char Ps[128 * 256];
    __shared__ float mrow[128];

    const int bid = blockIdx.x;
    const int b = bid & 511;
    const int h = bid >> 9;
    const int tid = threadIdx.x;
    const int w = tid >> 6, l = tid & 63;
    const int l15 = l & 15, l4 = l >> 4;
    const int R0 = w * 16;

    if (tid < 128) mrow[tid] = mask[b * 128 + tid];

    const bf16* A  = inp + (size_t)(b * 128) * 512;
    const bf16* Wh = Wqkv_t + (size_t)h * 192 * 512;
    const f32x4 fz = {0.f, 0.f, 0.f, 0.f};

    f32x4 acc[12];
#pragma unroll
    for (int n = 0; n < 12; n++) acc[n] = fz;
    const bf16* aptr = A + (size_t)(R0 + l15) * 512 + l4 * 8;
#pragma unroll 4
    for (int ks = 0; ks < 16; ks++) {
        bf16x8 af = *(const bf16x8*)(aptr + ks * 32);
#pragma unroll
        for (int n = 0; n < 12; n++) {
            bf16x8 bfr = *(const bf16x8*)(Wh + (size_t)(n * 16 + l15) * 512 + ks * 32 + l4 * 8);
            acc[n] = mfma16(af, bfr, acc[n]);
        }
    }
#pragma unroll
    for (int n = 0; n < 12; n++) {
        int col = n * 16 + l15;
        float bias = bQKV[h * 192 + col];
#pragma unroll
        for (int r = 0; r < 4; r++) {
            int row = R0 + l4 * 4 + r;
            bf16 val = (bf16)(acc[n][r] + bias);
            if (n < 4) {
                *(bf16*)(Qs + row * 128 + SWZ(col * 2, row)) = val;
            } else if (n < 8) {
                *(bf16*)(Ks + row * 128 + SWZ((col - 64) * 2, row)) = val;
            } else {
                int d = col - 128;
                *(bf16*)(VTs + d * 256 + SWZ(row * 2, d)) = val;
            }
        }
    }
    __syncthreads();

    f32x4 accL[8];
#pragma unroll
    for (int n = 0; n < 8; n++) accL[n] = fz;
#pragma unroll
    for (int ks = 0; ks < 2; ks++) {
        int k = ks * 32 + l4 * 8;
        int qrow = R0 + l15;
        bf16x8 af = *(const bf16x8*)(Qs + qrow * 128 + SWZ(k * 2, qrow));
#pragma unroll
        for (int nt = 0; nt < 8; nt++) {
            int krow = nt * 16 + l15;
            bf16x8 bfr = *(const bf16x8*)(Ks + krow * 128 + SWZ(k * 2, krow));
            accL[nt] = mfma16(af, bfr, accL[nt]);
        }
    }
    float pv[32];
#pragma unroll
    for (int r = 0; r < 4; r++) {
        float mx = -1e30f;
#pragma unroll
        for (int nt = 0; nt < 8; nt++) {
            int colk = nt * 16 + l15;
            float v = accL[nt][r] * 0.125f - (1.0f - mrow[colk]) * 1e10f;
            pv[nt * 4 + r] = v;
            mx = fmaxf(mx, v);
        }
#pragma unroll
        for (int m = 1; m < 16; m <<= 1) mx = fmaxf(mx, __shfl_xor(mx, m, 64));
        float sum = 0.f;
#pragma unroll
        for (int nt = 0; nt < 8; nt++) {
            int colk = nt * 16 + l15;
            float e = __expf(pv[nt * 4 + r] - mx) * mrow[colk];
            pv[nt * 4 + r] = e;
            sum += e;
        }
#pragma unroll
        for (int m = 1; m < 16; m <<= 1) sum += __shfl_xor(sum, m, 64);
        float inv = 1.0f / (sum + 1e-10f);
        int prow = R0 + l4 * 4 + r;
#pragma unroll
        for (int nt = 0; nt < 8; nt++) {
            bf16 pb = (bf16)(pv[nt * 4 + r] * inv);
            *(bf16*)(Ps + prow * 256 + SWZ((nt * 16 + l15) * 2, prow)) = pb;
        }
    }
    __syncthreads();

    f32x4 accO[4];
#pragma unroll
    for (int n = 0; n < 4; n++) accO[n] = fz;
#pragma unroll
    for (int ks = 0; ks < 4; ks++) {
        int k = ks * 32 + l4 * 8;
        int prow = R0 + l15;
        bf16x8 af = *(const bf16x8*)(Ps + prow * 256 + SWZ(k * 2, prow));
#pragma unroll
        for (int nt = 0; nt < 4; nt++) {
            int d = nt * 16 + l15;
            bf16x8 bfr = *(const bf16x8*)(VTs + d * 256 + SWZ(k * 2, d));
            accO[nt] = mfma16(af, bfr, accO[nt]);
        }
    }
    bf16* outp = att + (size_t)(b * 128) * 512 + h * 64;
#pragma unroll
    for (int nt = 0; nt < 4; nt++) {
        int d = nt * 16 + l15;
#pragma unroll
        for (int r = 0; r < 4; r++) {
            int e = R0 + l4 * 4 + r;
            outp[(size_t)e * 512 + d] = (bf16)accO[nt][r];
        }
    }
}

__global__ __launch_bounds__(512) void mlp_kernel(
    const bf16* __restrict__ att, const bf16* __restrict__ Wmlp_t,
    const float* __restrict__ bmlp, const float* __restrict__ x,
    const float* __restrict__ mask, const float* __restrict__ gpost,
    const float* __restrict__ bpost, float* __restrict__ out)
{
    __shared__ float pool[512];
    __shared__ float gb[1024];
    __shared__ float mrow[128];
    __shared__ float msum_s;

    const int b = blockIdx.x;
    const int tid = threadIdx.x;
    const int w = tid >> 6, l = tid & 63;
    const int l15 = l & 15, l4 = l >> 4;
    const int R0 = w * 16;

    pool[tid] = 0.f;
    gb[tid] = gpost[tid];
    gb[512 + tid] = bpost[tid];
    if (tid < 128) mrow[tid] = mask[b * 128 + tid];
    __syncthreads();
    if (w == 0) {
        float v = mrow[l] + mrow[64 + l];
#pragma unroll
        for (int m = 1; m < 64; m <<= 1) v += __shfl_xor(v, m, 64);
        if (l == 0) msum_s = v;
    }

    const f32x4 fz = {0.f, 0.f, 0.f, 0.f};
    f32x4 acc[32];
#pragma unroll
    for (int n = 0; n < 32; n++) acc[n] = fz;
    const bf16* Ab = att + (size_t)(b * 128 + R0 + l15) * 512 + l4 * 8;
#pragma unroll 2
    for (int ks = 0; ks < 16; ks++) {
        bf16x8 af = *(const bf16x8*)(Ab + ks * 32);
#pragma unroll
        for (int nt = 0; nt < 32; nt++) {
            bf16x8 bfr = *(const bf16x8*)(Wmlp_t + (size_t)(nt * 16 + l15) * 512 + ks * 32 + l4 * 8);
            acc[nt] = mfma16(af, bfr, acc[nt]);
        }
    }
#pragma unroll
    for (int nt = 0; nt < 32; nt++) {
        int col = nt * 16 + l15;
        float bb = bmlp[col];
#pragma unroll
        for (int r = 0; r < 4; r++) {
            int row = R0 + l4 * 4 + r;
            acc[nt][r] = acc[nt][r] + bb + x[((size_t)b * 128 + row) * 512 + col];
        }
    }
    float mu[4], rs[4];
#pragma unroll
    for (int r = 0; r < 4; r++) {
        float s = 0.f, ss = 0.f;
#pragma unroll
        for (int nt = 0; nt < 32; nt++) {
            float v = acc[nt][r];
            s += v; ss += v * v;
        }
#pragma unroll
        for (int m = 1; m < 16; m <<= 1) {
            s  += __shfl_xor(s, m, 64);
            ss += __shfl_xor(ss, m, 64);
        }
        float m_ = s * (1.f / 512.f);
        mu[r] = m_;
        rs[r] = rsqrtf(ss * (1.f / 512.f) - m_ * m_ + 1e-3f);
    }
#pragma unroll
    for (int nt = 0; nt < 32; nt++) {
        int col = nt * 16 + l15;
        float g = gb[col], bb = gb[512 + col];
        float s = 0.f;
#pragma unroll
        for (int r = 0; r < 4; r++) {
            int row = R0 + l4 * 4 + r;
            float y = (acc[nt][r] - mu[r]) * rs[r] * g + bb;
            s += y * mrow[row];
        }
        atomicAdd(&pool[col], s);
    }
    __syncthreads();
    out[(size_t)b * 512 + tid] = pool[tid] / (msum_s + 1e-5f);
}

// ---------------------------------------------------------------------------
extern "C" void kernel_launch(void* const* d_in, const int* in_sizes, int n_in,
                              void* d_out, int out_size, void* d_ws, size_t ws_size,
                              hipStream_t stream)
{
    const float* x     = (const float*)d_in[0];
    const float* mask  = (const float*)d_in[1];
    const float* Wqk   = (const float*)d_in[2];
    const float* bqk   = (const float*)d_in[3];
    const float* Wv    = (const float*)d_in[4];
    const float* bv    = (const float*)d_in[5];
    const float* Wmlp  = (const float*)d_in[6];
    const float* bmlp  = (const float*)d_in[7];
    const float* gpre  = (const float*)d_in[8];
    const float* bpre  = (const float*)d_in[9];
    const float* gpost = (const float*)d_in[10];
    const float* bpost = (const float*)d_in[11];
    float* out = (float*)d_out;
    char* ws = (char*)d_ws;

    const size_t NEED_SPLIT = 270538752;   // 256MiB buffers + 2MiB weights + 6KiB bias
    if (ws_size >= NEED_SPLIT) {
        bf16*  q      = (bf16*)ws;                               // 64 MiB
        bf16*  kbuf   = (bf16*)(ws + (size_t)67108864);          // 64 MiB
        bf16*  vt     = (bf16*)(ws + (size_t)134217728);         // 64 MiB
        bf16*  inp    = (bf16*)(ws + (size_t)201326592);         // 64 MiB (att aliases)
        bf16*  att    = inp;
        bf16*  y      = (bf16*)ws;                               // 64 MiB, aliases q (dead)
        bf16*  Wqkv_s = (bf16*)(ws + (size_t)268435456);         // 1.5 MiB
        bf16*  Wmlp_t = (bf16*)(ws + (size_t)270008320);         // 0.5 MiB
        float* bQKV   = (float*)(ws + (size_t)270532608);        // 6 KiB

        prep_split_kernel<<<4103, 256, 0, stream>>>(Wqk, bqk, Wv, bv, Wmlp, Wqkv_s, Wmlp_t, bQKV);
        ln_kernel<<<16384, 256, 0, stream>>>(x, gpre, bpre, inp);
        qkv_gemm_kernel<<<6144, 512, 0, stream>>>(inp, Wqkv_s, bQKV, q, kbuf, vt);
        attn_fused_kernel<<<512, 512, 0, stream>>>(q, kbuf, vt, mask, att);
        mlp_gemm_kernel<<<2048, 512, 0, stream>>>(att, Wmlp_t, bmlp, y);
        pool_kernel<<<512, 512, 0, stream>>>(y, x, mask, gpost, bpost, out);
    } else {
        bf16*  inp    = (bf16*)ws;                                   // 64 MiB
        bf16*  att    = (bf16*)(ws + 67108864);                      // 64 MiB
        bf16*  Wqkv_t = (bf16*)(ws + 134217728);                     // 1.5 MiB
        bf16*  Wmlp_t = (bf16*)(ws + 134217728 + 1572864);           // 0.5 MiB
        float* bQKV   = (float*)(ws + 134217728 + 1572864 + 524288); // 6 KiB

        prep_kernel<<<4103, 256, 0, stream>>>(Wqk, bqk, Wv, bv, Wmlp, Wqkv_t, Wmlp_t, bQKV);
        ln_kernel<<<16384, 256, 0, stream>>>(x, gpre, bpre, inp);
        attn_kernel<<<4096, 512, 0, stream>>>(inp, mask, Wqkv_t, bQKV, att);
        mlp_kernel<<<512, 512, 0, stream>>>(att, Wmlp_t, bmlp, x, mask, gpost, bpost, out);
    }
}